// Round 12
// baseline (785.680 us; speedup 1.0000x reference)
//
#include <hip/hip_runtime.h>
#include <math.h>

typedef unsigned short ushort_t;
typedef unsigned int   uint_t;
typedef __attribute__((ext_vector_type(8)))  short bf16x8;
typedef __attribute__((ext_vector_type(16))) float f32x16;

#define NPTS   65536   // B*P
#define NV     5023
#define NVP    5120    // padded to 160 tiles of 32
#define NTILE  160
#define QTILE  40      // tiles per wave-quarter (4-way vertex split)
#define LATD   32
#define KF     110
#define FSTR   112     // feat row stride (uints)
#define MARGIN 1.5e-2f // >= 2*mfma_err(~2.5e-3) + exact-path err; 3x headroom

union U4 { uint_t u[4]; bf16x8 v; };

__device__ __forceinline__ ushort_t f2bf(float f) {
  union { float f; unsigned u; } x; x.f = f;
  unsigned r = x.u + 0x7fffu + ((x.u >> 16) & 1u);   // RNE
  return (ushort_t)(r >> 16);
}
__device__ __forceinline__ float bf2f(ushort_t u) {
  union { unsigned u; float f; } x; x.u = ((unsigned)u) << 16;
  return x.f;
}
__device__ __forceinline__ uint_t packsplit(float v) {
  const ushort_t h = f2bf(v);
  const ushort_t l = f2bf(v - bf2f(h));
  return (uint_t)h | ((uint_t)l << 16);
}

// exact double-angle step: (sin a, cos a) -> (sin 2a, cos 2a)  [r5-verified]
__device__ __forceinline__ void dbl_step(float& s, float& c) {
  const float t = s * c;
  const float cn = fmaf(-2.f * s, s, 1.f);
  s = t + t;
  c = cn;
}

// ---------------- Kernel 0: prep (weights + vertex MFMA-fragments) — r9 verbatim ----------------
__global__ __launch_bounds__(256) void k_prep(
    const float* __restrict__ dm,
    const float* __restrict__ w0, const float* __restrict__ w1,
    const float* __restrict__ w2, const float* __restrict__ w3,
    const float* __restrict__ w4, const float* __restrict__ w5,
    const float* __restrict__ w6, const float* __restrict__ w7,
    ushort_t* __restrict__ wsWh, ushort_t* __restrict__ wsWl,
    ushort_t* __restrict__ aFF, ushort_t* __restrict__ aFH,
    float4* __restrict__ vq)
{
  const int e = blockIdx.x * 256 + threadIdx.x;    // 576*256 = 147456 exactly
  {
    const int p = e >> 14, local = e & 16383;
    const int j   = local & 7;
    const int lh  = (local >> 3) & 1;
    const int l31 = (local >> 4) & 31;
    const int tn  = (local >> 9) & 3;
    const int ks  = (local >> 11) & 7;
    const int n = tn*32 + l31;
    const int k = ks*16 + lh*8 + j;
    float v;
    if (p == 0)      v = (k < KF) ? w0[n*110 + k] : 0.f;
    else if (p == 1) v = w1[n*128 + k];
    else if (p == 2) v = w2[n*128 + k];
    else if (p == 3) v = w3[n*128 + k];
    else if (p == 4) v = (k < KF) ? w4[n*238 + k] : 0.f;
    else if (p == 5) v = w4[n*238 + KF + k];
    else if (p == 6) v = w5[n*128 + k];
    else if (p == 7) v = w6[n*128 + k];
    else             v = w7[n*128 + k];
    const ushort_t h = f2bf(v);
    wsWh[e] = h;
    wsWl[e] = f2bf(v - bf2f(h));
  }
  if (e < 2*NVP) {
    const int b = (e >= NVP) ? 1 : 0;
    const int v = e - b*NVP;
    const float* __restrict__ dmb = dm + b*NV*3;
    float x = 0.f, y = 0.f, z = 0.f, wv = 3.0e38f;
    if (v < NV) {
      x = dmb[v*3+0]; y = dmb[v*3+1]; z = dmb[v*3+2];
      wv = fmaf(x,x, fmaf(y,y, z*z));                // EXACT t.w of r7 metric
    }
    const ushort_t hx = f2bf(x),  hy = f2bf(y),  hz = f2bf(z),  hw = f2bf(wv);
    const ushort_t lx = f2bf(x - bf2f(hx)), ly = f2bf(y - bf2f(hy));
    const ushort_t lz = f2bf(z - bf2f(hz)), lw = f2bf(wv - bf2f(hw));
    U4 F, H;
    F.u[0] = (uint_t)hx | ((uint_t)hy << 16);
    F.u[1] = (uint_t)hz | ((uint_t)hw << 16);
    F.u[2] = (uint_t)lx | ((uint_t)ly << 16);
    F.u[3] = (uint_t)lz | ((uint_t)lw << 16);
    H.u[0] = F.u[0]; H.u[1] = F.u[1]; H.u[2] = 0; H.u[3] = 0;
    *(bf16x8*)(aFF + (size_t)e*8) = F.v;
    *(bf16x8*)(aFH + (size_t)e*8) = H.v;
    vq[e] = make_float4(x, y, z, wv);
  }
}

// ---------------- Kernel 1: MFMA two-phase exact NN (4-way vertex split) + features ----------------
// 2048 blocks x 256 thr = 4 waves; 32 pts/block. Wave w scans vertex quarter w
// (tiles w*40..w*40+39); all 4 waves share the same 32 points (pt = g0 + l31).
// 8192 waves = 32 waves/CU = 8 waves/SIMD (launch_bounds pins VGPR<=64; r11 used 60
// at 4 waves/SIMD and 45% VALU — TLP was still the residual stall).
// Pass-A gmins merge via LDS (thr needs global min); pass-B (d2,idx) merge
// lexicographically over the 4 quarters in the features phase. Numerics r11-verified.
__device__ __forceinline__ float min16(const f32x16& d) {
  const float t0 = fminf(fminf(d[0],d[1]),   fminf(d[2],d[3]));
  const float t1 = fminf(fminf(d[4],d[5]),   fminf(d[6],d[7]));
  const float t2 = fminf(fminf(d[8],d[9]),   fminf(d[10],d[11]));
  const float t3 = fminf(fminf(d[12],d[13]), fminf(d[14],d[15]));
  return fminf(fminf(t0,t1), fminf(t2,t3));
}

__global__ __launch_bounds__(256, 8) void k_nnfeat(
    const float* __restrict__ pts, const float* __restrict__ dm,
    const float* __restrict__ cano, const float* __restrict__ lat,
    const ushort_t* __restrict__ aFF, const ushort_t* __restrict__ aFH,
    const float4* __restrict__ vq,
    uint_t* __restrict__ feat, float* __restrict__ base3)
{
  __shared__ float sMin[4][32];
  __shared__ float sDh[4][32];
  __shared__ int   sIh[4][32];

  const int tid = threadIdx.x;
  const int lane = tid & 63, w = tid >> 6;      // w = vertex quarter
  const int l31 = lane & 31, lh = lane >> 5;
  const int g0 = blockIdx.x * 32;
  const int b  = blockIdx.x >> 10;              // 1024 blocks per batch
  const int pt = g0 + l31;

  const float px = pts[pt*3+0], py = pts[pt*3+1], pz = pts[pt*3+2];
  const float p2 = fmaf(px,px, fmaf(py,py, pz*pz));

  // B fragment (per-lane, by lh) — r9-verified encoding
  const float tpx = -2.f*px, tpy = -2.f*py, tpz = -2.f*pz;
  const ushort_t hpx = f2bf(tpx), hpy = f2bf(tpy), hpz = f2bf(tpz);
  const ushort_t lpx = f2bf(tpx - bf2f(hpx));
  const ushort_t lpy = f2bf(tpy - bf2f(hpy));
  const ushort_t lpz = f2bf(tpz - bf2f(hpz));
  U4 Bh, Bl;
  Bh.u[0] = (uint_t)hpx | ((uint_t)hpy << 16);
  Bh.u[1] = (uint_t)hpz | (0x3F80u << 16);      // bf16(1.0)
  Bh.u[2] = Bh.u[0]; Bh.u[3] = Bh.u[1];
  Bl.u[0] = (uint_t)lpx | ((uint_t)lpy << 16);
  Bl.u[1] = (uint_t)lpz;
  Bl.u[2] = 0; Bl.u[3] = 0;
  const bf16x8 bfrag = lh ? Bl.v : Bh.v;

  // this wave's tile range: [w*40, w*40+40)
  const ushort_t* __restrict__ aBase = (lh ? aFH : aFF)
      + (size_t)b * NVP * 8 + (size_t)w * QTILE * 32 * 8;
  const float4*   __restrict__ vqb   = vq + (size_t)b * NVP;
  const int vho = w * QTILE * 32;               // vertex offset of this quarter

  const f32x16 zacc = (f32x16)(0.f);

  // ---- pass A: s-min over this wave's 40 tiles (batched, prefetched) ----
  float gmin = 3.0e38f;
  bf16x8 ap0, ap1, ap2, ap3, an0, an1, an2, an3;
  ap0 = *(const bf16x8*)(aBase + (size_t)(0*32 + l31)*8);
  ap1 = *(const bf16x8*)(aBase + (size_t)(1*32 + l31)*8);
  ap2 = *(const bf16x8*)(aBase + (size_t)(2*32 + l31)*8);
  ap3 = *(const bf16x8*)(aBase + (size_t)(3*32 + l31)*8);
  #pragma unroll 2
  for (int tb = 0; tb < QTILE/4; ++tb) {
    const int t0 = tb*4;
    if (tb + 1 < QTILE/4) {
      an0 = *(const bf16x8*)(aBase + (size_t)((t0+4)*32 + l31)*8);
      an1 = *(const bf16x8*)(aBase + (size_t)((t0+5)*32 + l31)*8);
      an2 = *(const bf16x8*)(aBase + (size_t)((t0+6)*32 + l31)*8);
      an3 = *(const bf16x8*)(aBase + (size_t)((t0+7)*32 + l31)*8);
    }
    const f32x16 d0 = __builtin_amdgcn_mfma_f32_32x32x16_bf16(ap0, bfrag, zacc, 0,0,0);
    const f32x16 d1 = __builtin_amdgcn_mfma_f32_32x32x16_bf16(ap1, bfrag, zacc, 0,0,0);
    const f32x16 d2 = __builtin_amdgcn_mfma_f32_32x32x16_bf16(ap2, bfrag, zacc, 0,0,0);
    const f32x16 d3 = __builtin_amdgcn_mfma_f32_32x32x16_bf16(ap3, bfrag, zacc, 0,0,0);
    const float m0 = min16(d0), m1 = min16(d1), m2 = min16(d2), m3 = min16(d3);
    gmin = fminf(gmin, fminf(fminf(m0,m1), fminf(m2,m3)));
    ap0 = an0; ap1 = an1; ap2 = an2; ap3 = an3;
  }
  gmin = fminf(gmin, __shfl_xor(gmin, 32, 64));  // combine lh halves (rows split)
  if (lane < 32) sMin[w][l31] = gmin;
  __syncthreads();
  const float thr = fminf(fminf(sMin[0][l31], sMin[1][l31]),
                          fminf(sMin[2][l31], sMin[3][l31])) + MARGIN;

  // ---- pass B: exact candidates over this wave's 40 tiles ----
  float bs = 3.4e38f; int bi = 0;
  ap0 = *(const bf16x8*)(aBase + (size_t)(0*32 + l31)*8);
  ap1 = *(const bf16x8*)(aBase + (size_t)(1*32 + l31)*8);
  ap2 = *(const bf16x8*)(aBase + (size_t)(2*32 + l31)*8);
  ap3 = *(const bf16x8*)(aBase + (size_t)(3*32 + l31)*8);
  #pragma unroll 1
  for (int tb = 0; tb < QTILE/4; ++tb) {
    const int t0 = tb*4;
    if (tb + 1 < QTILE/4) {
      an0 = *(const bf16x8*)(aBase + (size_t)((t0+4)*32 + l31)*8);
      an1 = *(const bf16x8*)(aBase + (size_t)((t0+5)*32 + l31)*8);
      an2 = *(const bf16x8*)(aBase + (size_t)((t0+6)*32 + l31)*8);
      an3 = *(const bf16x8*)(aBase + (size_t)((t0+7)*32 + l31)*8);
    }
    f32x16 dd[4];
    dd[0] = __builtin_amdgcn_mfma_f32_32x32x16_bf16(ap0, bfrag, zacc, 0,0,0);
    dd[1] = __builtin_amdgcn_mfma_f32_32x32x16_bf16(ap1, bfrag, zacc, 0,0,0);
    dd[2] = __builtin_amdgcn_mfma_f32_32x32x16_bf16(ap2, bfrag, zacc, 0,0,0);
    dd[3] = __builtin_amdgcn_mfma_f32_32x32x16_bf16(ap3, bfrag, zacc, 0,0,0);
    #pragma unroll
    for (int i = 0; i < 4; ++i) {
      const f32x16 d = dd[i];
      float q4[4];
      q4[0] = fminf(fminf(d[0],d[1]),   fminf(d[2],d[3]));
      q4[1] = fminf(fminf(d[4],d[5]),   fminf(d[6],d[7]));
      q4[2] = fminf(fminf(d[8],d[9]),   fminf(d[10],d[11]));
      q4[3] = fminf(fminf(d[12],d[13]), fminf(d[14],d[15]));
      const float tm = fminf(fminf(q4[0],q4[1]), fminf(q4[2],q4[3]));
      if (tm <= thr) {
        const int t = t0 + i;
        #pragma unroll
        for (int q = 0; q < 4; ++q) {
          if (q4[q] <= thr) {
            #pragma unroll
            for (int rr = 0; rr < 4; ++rr) {
              const int r = q*4 + rr;
              if (d[r] <= thr) {
                const int row = (r & 3) + 8*(r >> 2) + 4*lh;   // C/D row map (verified)
                const int v = vho + t*32 + row;
                const float4 qv = vqb[v];
                const float dot = fmaf(px, qv.x, fmaf(py, qv.y, pz*qv.z));
                float d2 = fmaf(-2.f, dot, p2 + qv.w);          // r7 metric, exact
                d2 = fmaxf(d2, 0.f);
                if (d2 < bs || (d2 == bs && v < bi)) { bs = d2; bi = v; }
              }
            }
          }
        }
      }
    }
    ap0 = an0; ap1 = an1; ap2 = an2; ap3 = an3;
  }
  // merge the lh pair (lexicographic (d2, idx))
  {
    const float ob = __shfl_xor(bs, 32, 64);
    const int   oi = __shfl_xor(bi, 32, 64);
    if (ob < bs || (ob == bs && oi < bi)) { bs = ob; bi = oi; }
  }
  if (lane < 32) { sDh[w][l31] = bs; sIh[w][l31] = bi; }
  __syncthreads();

  // ---- features: 8 wave-uniform slices per point ----
  const int p = tid & 31, slice = tid >> 5;
  const int g = g0 + p;
  float wd = sDh[0][p]; int wi = sIh[0][p];
  #pragma unroll
  for (int qq = 1; qq < 4; ++qq) {
    const float od = sDh[qq][p]; const int oi = sIh[qq][p];
    if (od < wd || (od == wd && oi < wi)) { wd = od; wi = oi; }
  }
  const float* __restrict__ dmb = dm + b * NV * 3;

  const float qx = pts[g*3+0], qy = pts[g*3+1], qz = pts[g*3+2];
  const float wgt = expf(-wd);
  const float sx = (cano[wi*3+0] - dmb[wi*3+0]) * wgt;
  const float sy = (cano[wi*3+1] - dmb[wi*3+1]) * wgt;
  const float sz = (cano[wi*3+2] - dmb[wi*3+2]) * wgt;

  uint_t* __restrict__ fr = feat + (size_t)g * FSTR;

  if (slice == 0) {
    base3[g*3+0] = qx + sx; base3[g*3+1] = qy + sy; base3[g*3+2] = qz + sz;
    fr[0] = packsplit(qx); fr[1] = packsplit(qy); fr[2] = packsplit(qz);
    float s0,c0,s1,c1,s2,c2;
    sincosf(qx,&s0,&c0); sincosf(qy,&s1,&c1); sincosf(qz,&s2,&c2);
    #pragma unroll
    for (int f = 0; f < 3; ++f) {
      const int k = 3 + 6*f;
      fr[k+0]=packsplit(s0); fr[k+1]=packsplit(s1); fr[k+2]=packsplit(s2);
      fr[k+3]=packsplit(c0); fr[k+4]=packsplit(c1); fr[k+5]=packsplit(c2);
      if (f < 2) { dbl_step(s0,c0); dbl_step(s1,c1); dbl_step(s2,c2); }
    }
  } else if (slice == 1) {
    float s0,c0,s1,c1,s2,c2;
    sincosf(qx*8.f,&s0,&c0); sincosf(qy*8.f,&s1,&c1); sincosf(qz*8.f,&s2,&c2);
    #pragma unroll
    for (int f = 3; f < 7; ++f) {
      const int k = 3 + 6*f;
      fr[k+0]=packsplit(s0); fr[k+1]=packsplit(s1); fr[k+2]=packsplit(s2);
      fr[k+3]=packsplit(c0); fr[k+4]=packsplit(c1); fr[k+5]=packsplit(c2);
      if (f < 6) { dbl_step(s0,c0); dbl_step(s1,c1); dbl_step(s2,c2); }
    }
  } else if (slice == 2) {
    float s0,c0,s1,c1,s2,c2;
    sincosf(qx*128.f,&s0,&c0); sincosf(qy*128.f,&s1,&c1); sincosf(qz*128.f,&s2,&c2);
    #pragma unroll
    for (int f = 7; f < 10; ++f) {
      const int k = 3 + 6*f;
      fr[k+0]=packsplit(s0); fr[k+1]=packsplit(s1); fr[k+2]=packsplit(s2);
      fr[k+3]=packsplit(c0); fr[k+4]=packsplit(c1); fr[k+5]=packsplit(c2);
      if (f < 9) { dbl_step(s0,c0); dbl_step(s1,c1); dbl_step(s2,c2); }
    }
  } else if (slice == 3) {
    fr[63]=packsplit(sx); fr[64]=packsplit(sy); fr[65]=packsplit(sz);
    float s0,c0,s1,c1,s2,c2;
    sincosf(sx,&s0,&c0); sincosf(sy,&s1,&c1); sincosf(sz,&s2,&c2);
    #pragma unroll
    for (int f = 0; f < 2; ++f) {
      const int k = 66 + 6*f;
      fr[k+0]=packsplit(s0); fr[k+1]=packsplit(s1); fr[k+2]=packsplit(s2);
      fr[k+3]=packsplit(c0); fr[k+4]=packsplit(c1); fr[k+5]=packsplit(c2);
      if (f < 1) { dbl_step(s0,c0); dbl_step(s1,c1); dbl_step(s2,c2); }
    }
    fr[110] = 0; fr[111] = 0;
  } else {
    // slices 4..7: latent 8 each
    const int j0 = (slice - 4) * 8;
    #pragma unroll
    for (int j = 0; j < 8; ++j) fr[78 + j0 + j] = packsplit(lat[g*LATD + j0 + j]);
  }
}

// ------------- Kernel 2: register-resident MLP (operand-swapped MFMA) — r3 verbatim -------------

__device__ __forceinline__ void zero4(f32x16 (&a)[4]) {
  #pragma unroll
  for (int i = 0; i < 4; ++i) a[i] = (f32x16)(0.f);
}

__device__ __forceinline__ void load_feat_frags(
    const uint_t* __restrict__ fr, bf16x8 (&Xh)[8], bf16x8 (&Xl)[8], int lh)
{
  #pragma unroll
  for (int ks = 0; ks < 7; ++ks) {
    const int k0 = ks*16 + lh*8;
    const uint4 ua = *(const uint4*)(fr + k0);
    const uint4 ub = *(const uint4*)(fr + k0 + 4);
    U4 H, L;
    H.u[0] = (ua.x & 0xffffu) | (ua.y << 16);
    H.u[1] = (ua.z & 0xffffu) | (ua.w << 16);
    H.u[2] = (ub.x & 0xffffu) | (ub.y << 16);
    H.u[3] = (ub.z & 0xffffu) | (ub.w << 16);
    L.u[0] = (ua.x >> 16) | (ua.y & 0xffff0000u);
    L.u[1] = (ua.z >> 16) | (ua.w & 0xffff0000u);
    L.u[2] = (ub.x >> 16) | (ub.y & 0xffff0000u);
    L.u[3] = (ub.z >> 16) | (ub.w & 0xffff0000u);
    Xh[ks] = H.v; Xl[ks] = L.v;
  }
}

__device__ __forceinline__ void load_slab(bf16x8 (&wh)[4], bf16x8 (&wl)[4],
    const ushort_t* __restrict__ Wh, const ushort_t* __restrict__ Wl,
    int ks, int l31, int lh)
{
  const int lo = l31*16 + lh*8;
  #pragma unroll
  for (int tn = 0; tn < 4; ++tn) {
    const int off = (ks*4 + tn)*512 + lo;
    wh[tn] = *(const bf16x8*)(Wh + off);
    wl[tn] = *(const bf16x8*)(Wl + off);
  }
}

__device__ __forceinline__ void mfma_slab(f32x16 (&acc)[4],
    const bf16x8 (&wh)[4], const bf16x8 (&wl)[4],
    const bf16x8& xh, const bf16x8& xl)
{
  #pragma unroll
  for (int tn = 0; tn < 4; ++tn) {
    acc[tn] = __builtin_amdgcn_mfma_f32_32x32x16_bf16(wh[tn], xh, acc[tn], 0,0,0);
    acc[tn] = __builtin_amdgcn_mfma_f32_32x32x16_bf16(wl[tn], xh, acc[tn], 0,0,0);
    acc[tn] = __builtin_amdgcn_mfma_f32_32x32x16_bf16(wh[tn], xl, acc[tn], 0,0,0);
  }
}

template<int NKS, bool TAIL>
__device__ __forceinline__ void run_panel(f32x16 (&acc)[4],
    const ushort_t* __restrict__ Wh, const ushort_t* __restrict__ Wl,
    const ushort_t* __restrict__ WhN, const ushort_t* __restrict__ WlN,
    bf16x8 (&wbh)[2][4], bf16x8 (&wbl)[2][4],
    const bf16x8 (&Xh)[8], const bf16x8 (&Xl)[8], int l31, int lh)
{
  #pragma unroll
  for (int ks = 0; ks < NKS; ++ks) {
    const int b = ks & 1;
    mfma_slab(acc, wbh[b], wbl[b], Xh[ks], Xl[ks]);
    if (ks + 2 < NKS) {
      load_slab(wbh[b], wbl[b], Wh, Wl, ks + 2, l31, lh);
    } else if (TAIL) {
      load_slab(wbh[b], wbl[b], WhN, WlN, ks & 1, l31, lh);
    }
  }
}

__device__ __forceinline__ void bias_relu(f32x16 (&acc)[4],
    const float* __restrict__ bias, int lh)
{
  #pragma unroll
  for (int tn = 0; tn < 4; ++tn)
    #pragma unroll
    for (int b = 0; b < 4; ++b) {
      const float4 b4 = *(const float4*)(bias + tn*32 + 8*b + 4*lh);
      acc[tn][4*b+0] = fmaxf(acc[tn][4*b+0] + b4.x, 0.f);
      acc[tn][4*b+1] = fmaxf(acc[tn][4*b+1] + b4.y, 0.f);
      acc[tn][4*b+2] = fmaxf(acc[tn][4*b+2] + b4.z, 0.f);
      acc[tn][4*b+3] = fmaxf(acc[tn][4*b+3] + b4.w, 0.f);
    }
}

__device__ __forceinline__ void build_frags(const f32x16 (&acc)[4],
    bf16x8 (&Xh)[8], bf16x8 (&Xl)[8], int lh)
{
  #pragma unroll
  for (int ks = 0; ks < 8; ++ks) {
    const int tn = ks >> 1;
    const int rb = 8*(ks & 1);
    const float f0 = acc[tn][rb+0], f1 = acc[tn][rb+1];
    const float f2 = acc[tn][rb+2], f3 = acc[tn][rb+3];
    const float f4 = acc[tn][rb+4], f5 = acc[tn][rb+5];
    const float f6 = acc[tn][rb+6], f7 = acc[tn][rb+7];
    const ushort_t h0=f2bf(f0), h1=f2bf(f1), h2=f2bf(f2), h3=f2bf(f3);
    const ushort_t h4=f2bf(f4), h5=f2bf(f5), h6=f2bf(f6), h7=f2bf(f7);
    const uint_t hA0 = (uint_t)h0 | ((uint_t)h1 << 16);
    const uint_t hA1 = (uint_t)h2 | ((uint_t)h3 << 16);
    const uint_t hB0 = (uint_t)h4 | ((uint_t)h5 << 16);
    const uint_t hB1 = (uint_t)h6 | ((uint_t)h7 << 16);
    const uint_t lA0 = (uint_t)f2bf(f0 - bf2f(h0)) | ((uint_t)f2bf(f1 - bf2f(h1)) << 16);
    const uint_t lA1 = (uint_t)f2bf(f2 - bf2f(h2)) | ((uint_t)f2bf(f3 - bf2f(h3)) << 16);
    const uint_t lB0 = (uint_t)f2bf(f4 - bf2f(h4)) | ((uint_t)f2bf(f5 - bf2f(h5)) << 16);
    const uint_t lB1 = (uint_t)f2bf(f6 - bf2f(h6)) | ((uint_t)f2bf(f7 - bf2f(h7)) << 16);
    const uint_t sh0 = lh ? hA0 : hB0, sh1 = lh ? hA1 : hB1;
    const uint_t sl0 = lh ? lA0 : lB0, sl1 = lh ? lA1 : lB1;
    const uint_t rh0 = __shfl_xor(sh0, 32, 64), rh1 = __shfl_xor(sh1, 32, 64);
    const uint_t rl0 = __shfl_xor(sl0, 32, 64), rl1 = __shfl_xor(sl1, 32, 64);
    U4 H, L;
    H.u[0] = lh ? rh0 : hA0;  H.u[1] = lh ? rh1 : hA1;
    H.u[2] = lh ? hB0 : rh0;  H.u[3] = lh ? hB1 : rh1;
    L.u[0] = lh ? rl0 : lA0;  L.u[1] = lh ? rl1 : lA1;
    L.u[2] = lh ? lB0 : rl0;  L.u[3] = lh ? lB1 : rl1;
    Xh[ks] = H.v; Xl[ks] = L.v;
  }
}

__global__ __launch_bounds__(256, 2) void k_mlp(
    const uint_t* __restrict__ feat, const float* __restrict__ base3,
    const ushort_t* __restrict__ wsWh, const ushort_t* __restrict__ wsWl,
    const float* __restrict__ b0, const float* __restrict__ b1,
    const float* __restrict__ b2, const float* __restrict__ b3,
    const float* __restrict__ b4, const float* __restrict__ b5,
    const float* __restrict__ b6, const float* __restrict__ b7,
    const float* __restrict__ w_out, const float* __restrict__ b_out,
    float* __restrict__ out)
{
  __shared__ __align__(16) float sF[4][32*132];   // per-wave transpose buf
  __shared__ __align__(16) float sB[8*128 + 384 + 4];

  const int tid  = threadIdx.x;
  const int lane = tid & 63, wid = tid >> 6;
  const int l31 = lane & 31, lh = lane >> 5;
  const int p0 = blockIdx.x * 128 + wid * 32;

  {
    const float* bsp[8] = {b0,b1,b2,b3,b4,b5,b6,b7};
    if (tid < 128) {
      #pragma unroll
      for (int l = 0; l < 8; ++l) sB[l*128 + tid] = bsp[l][tid];
    }
    for (int i = tid; i < 384; i += 256) sB[1024 + i] = w_out[i];
    if (tid < 3) sB[1408 + tid] = b_out[tid];
  }

  const uint_t* __restrict__ fr = feat + (size_t)(p0 + l31) * FSTR;

  bf16x8 Xh[8], Xl[8];
  bf16x8 wbh[2][4], wbl[2][4];
  f32x16 acc[4];

  load_slab(wbh[0], wbl[0], wsWh, wsWl, 0, l31, lh);
  load_slab(wbh[1], wbl[1], wsWh, wsWl, 1, l31, lh);
  load_feat_frags(fr, Xh, Xl, lh);
  __syncthreads();

  zero4(acc);
  run_panel<7,true>(acc, wsWh + 0*16384, wsWl + 0*16384,
                         wsWh + 1*16384, wsWl + 1*16384, wbh, wbl, Xh, Xl, l31, lh);
  bias_relu(acc, sB + 0*128, lh);
  build_frags(acc, Xh, Xl, lh);

  zero4(acc);
  run_panel<8,true>(acc, wsWh + 1*16384, wsWl + 1*16384,
                         wsWh + 2*16384, wsWl + 2*16384, wbh, wbl, Xh, Xl, l31, lh);
  bias_relu(acc, sB + 1*128, lh);
  build_frags(acc, Xh, Xl, lh);

  zero4(acc);
  run_panel<8,true>(acc, wsWh + 2*16384, wsWl + 2*16384,
                         wsWh + 3*16384, wsWl + 3*16384, wbh, wbl, Xh, Xl, l31, lh);
  bias_relu(acc, sB + 2*128, lh);
  build_frags(acc, Xh, Xl, lh);

  zero4(acc);
  run_panel<8,true>(acc, wsWh + 3*16384, wsWl + 3*16384,
                         wsWh + 5*16384, wsWl + 5*16384, wbh, wbl, Xh, Xl, l31, lh);
  bias_relu(acc, sB + 3*128, lh);
  build_frags(acc, Xh, Xl, lh);

  zero4(acc);
  run_panel<8,true>(acc, wsWh + 5*16384, wsWl + 5*16384,
                         wsWh + 4*16384, wsWl + 4*16384, wbh, wbl, Xh, Xl, l31, lh);
  load_feat_frags(fr, Xh, Xl, lh);
  run_panel<7,true>(acc, wsWh + 4*16384, wsWl + 4*16384,
                         wsWh + 6*16384, wsWl + 6*16384, wbh, wbl, Xh, Xl, l31, lh);
  bias_relu(acc, sB + 4*128, lh);
  build_frags(acc, Xh, Xl, lh);

  zero4(acc);
  run_panel<8,true>(acc, wsWh + 6*16384, wsWl + 6*16384,
                         wsWh + 7*16384, wsWl + 7*16384, wbh, wbl, Xh, Xl, l31, lh);
  bias_relu(acc, sB + 5*128, lh);
  build_frags(acc, Xh, Xl, lh);

  zero4(acc);
  run_panel<8,true>(acc, wsWh + 7*16384, wsWl + 7*16384,
                         wsWh + 8*16384, wsWl + 8*16384, wbh, wbl, Xh, Xl, l31, lh);
  bias_relu(acc, sB + 6*128, lh);
  build_frags(acc, Xh, Xl, lh);

  zero4(acc);
  run_panel<8,false>(acc, wsWh + 8*16384, wsWl + 8*16384,
                          (const ushort_t*)0, (const ushort_t*)0, wbh, wbl, Xh, Xl, l31, lh);

  float* __restrict__ sFw = &sF[wid][0];
  #pragma unroll
  for (int tn = 0; tn < 4; ++tn)
    #pragma unroll
    for (int b = 0; b < 4; ++b) {
      const int n0 = tn*32 + 8*b + 4*lh;
      const float4 bv = *(const float4*)(sB + 7*128 + n0);
      const float v0 = acc[tn][4*b+0] + bv.x;
      const float v1 = acc[tn][4*b+1] + bv.y;
      const float v2 = acc[tn][4*b+2] + bv.z;
      const float v3 = acc[tn][4*b+3] + bv.w;
      *(float4*)(sFw + l31*132 + n0) = make_float4(v0, v1, v2, v3);
      acc[tn][4*b+0] = fmaxf(v0, 0.f);
      acc[tn][4*b+1] = fmaxf(v1, 0.f);
      acc[tn][4*b+2] = fmaxf(v2, 0.f);
      acc[tn][4*b+3] = fmaxf(v3, 0.f);
    }

  asm volatile("s_waitcnt lgkmcnt(0)" ::: "memory");
  __builtin_amdgcn_sched_barrier(0);

  float* __restrict__ out1 = out + (size_t)NPTS * 3;
  #pragma unroll
  for (int i = 0; i < 16; ++i) {
    const int idx = i*64 + lane;
    const int p = idx >> 5, q = idx & 31;
    const float4 v = *(const float4*)(sFw + p*132 + q*4);
    *(float4*)(out1 + (size_t)(p0 + p)*128 + q*4) = v;
  }

  float dotc[3];
  #pragma unroll
  for (int c = 0; c < 3; ++c) {
    float a = 0.f;
    #pragma unroll
    for (int tn = 0; tn < 4; ++tn)
      #pragma unroll
      for (int b = 0; b < 4; ++b) {
        const int n0 = tn*32 + 8*b + 4*lh;
        const float4 w4 = *(const float4*)(sB + 1024 + c*128 + n0);
        a = fmaf(acc[tn][4*b+0], w4.x, a);
        a = fmaf(acc[tn][4*b+1], w4.y, a);
        a = fmaf(acc[tn][4*b+2], w4.z, a);
        a = fmaf(acc[tn][4*b+3], w4.w, a);
      }
    a += __shfl_xor(a, 32, 64);
    dotc[c] = a;
  }
  if (lh == 0) {
    const int g = p0 + l31;
    #pragma unroll
    for (int c = 0; c < 3; ++c)
      out[g*3 + c] = base3[g*3 + c] + dotc[c] + sB[1408 + c];
  }
}

extern "C" void kernel_launch(void* const* d_in, const int* in_sizes, int n_in,
                              void* d_out, int out_size, void* d_ws, size_t ws_size,
                              hipStream_t stream)
{
  const float* pts  = (const float*)d_in[0];
  const float* dm   = (const float*)d_in[1];
  const float* cano = (const float*)d_in[2];
  const float* lat  = (const float*)d_in[3];
  const float* w[8]; const float* b[8];
  for (int i = 0; i < 8; ++i) {
    w[i] = (const float*)d_in[4 + 2*i];
    b[i] = (const float*)d_in[5 + 2*i];
  }
  const float* w_out = (const float*)d_in[20];
  const float* b_out = (const float*)d_in[21];
  float* out = (float*)d_out;

  // ws: feat [NPTS][112] uint (29.36MB) | base3 (786KB) | wsWh (288KB) | wsWl (288KB)
  //     | aFF 2*5120*16B (160KB) | aFH (160KB) | vq 2*5120*16B (160KB)
  uint_t*   feat  = (uint_t*)d_ws;
  float*    base3 = (float*)((char*)d_ws + (size_t)NPTS*FSTR*4);
  ushort_t* wsWh  = (ushort_t*)((char*)base3 + (size_t)NPTS*3*4);
  ushort_t* wsWl  = wsWh + 147456;
  ushort_t* aFF   = wsWl + 147456;
  ushort_t* aFH   = aFF + 2*NVP*8;
  float4*   vq    = (float4*)(aFH + 2*NVP*8);

  k_prep<<<576, 256, 0, stream>>>(dm,
      w[0],w[1],w[2],w[3],w[4],w[5],w[6],w[7], wsWh, wsWl, aFF, aFH, vq);
  k_nnfeat<<<2048, 256, 0, stream>>>(pts, dm, cano, lat, aFF, aFH, vq, feat, base3);
  k_mlp<<<NPTS/128, 256, 0, stream>>>(feat, base3, wsWh, wsWl,
      b[0],b[1],b[2],b[3],b[4],b[5],b[6],b[7], w_out, b_out, out);
}

// Round 13
// 607.822 us; speedup vs baseline: 1.2926x; 1.2926x over previous
//
#include <hip/hip_runtime.h>
#include <math.h>

typedef unsigned short ushort_t;
typedef unsigned int   uint_t;
typedef __attribute__((ext_vector_type(8)))  short bf16x8;
typedef __attribute__((ext_vector_type(16))) float f32x16;

#define NPTS   65536   // B*P
#define NV     5023
#define NVP    5120    // padded to 160 tiles of 32
#define NTILE  160
#define QTILE  40      // tiles per wave-quarter (4-way vertex split)
#define LATD   32
#define KF     110
#define FSTR   112     // feat row stride (uints)
#define MARGIN 1.5e-2f // >= 2*mfma_err(~2.5e-3) + exact-path err; 3x headroom

union U4 { uint_t u[4]; bf16x8 v; };

__device__ __forceinline__ ushort_t f2bf(float f) {
  union { float f; unsigned u; } x; x.f = f;
  unsigned r = x.u + 0x7fffu + ((x.u >> 16) & 1u);   // RNE
  return (ushort_t)(r >> 16);
}
__device__ __forceinline__ float bf2f(ushort_t u) {
  union { unsigned u; float f; } x; x.u = ((unsigned)u) << 16;
  return x.f;
}
__device__ __forceinline__ uint_t packsplit(float v) {
  const ushort_t h = f2bf(v);
  const ushort_t l = f2bf(v - bf2f(h));
  return (uint_t)h | ((uint_t)l << 16);
}

// exact double-angle step: (sin a, cos a) -> (sin 2a, cos 2a)  [r5-verified]
__device__ __forceinline__ void dbl_step(float& s, float& c) {
  const float t = s * c;
  const float cn = fmaf(-2.f * s, s, 1.f);
  s = t + t;
  c = cn;
}

// ---------------- Kernel 0: prep (weights + vertex MFMA-fragments) — r9 verbatim ----------------
__global__ __launch_bounds__(256) void k_prep(
    const float* __restrict__ dm,
    const float* __restrict__ w0, const float* __restrict__ w1,
    const float* __restrict__ w2, const float* __restrict__ w3,
    const float* __restrict__ w4, const float* __restrict__ w5,
    const float* __restrict__ w6, const float* __restrict__ w7,
    ushort_t* __restrict__ wsWh, ushort_t* __restrict__ wsWl,
    ushort_t* __restrict__ aFF, ushort_t* __restrict__ aFH,
    float4* __restrict__ vq)
{
  const int e = blockIdx.x * 256 + threadIdx.x;    // 576*256 = 147456 exactly
  {
    const int p = e >> 14, local = e & 16383;
    const int j   = local & 7;
    const int lh  = (local >> 3) & 1;
    const int l31 = (local >> 4) & 31;
    const int tn  = (local >> 9) & 3;
    const int ks  = (local >> 11) & 7;
    const int n = tn*32 + l31;
    const int k = ks*16 + lh*8 + j;
    float v;
    if (p == 0)      v = (k < KF) ? w0[n*110 + k] : 0.f;
    else if (p == 1) v = w1[n*128 + k];
    else if (p == 2) v = w2[n*128 + k];
    else if (p == 3) v = w3[n*128 + k];
    else if (p == 4) v = (k < KF) ? w4[n*238 + k] : 0.f;
    else if (p == 5) v = w4[n*238 + KF + k];
    else if (p == 6) v = w5[n*128 + k];
    else if (p == 7) v = w6[n*128 + k];
    else             v = w7[n*128 + k];
    const ushort_t h = f2bf(v);
    wsWh[e] = h;
    wsWl[e] = f2bf(v - bf2f(h));
  }
  if (e < 2*NVP) {
    const int b = (e >= NVP) ? 1 : 0;
    const int v = e - b*NVP;
    const float* __restrict__ dmb = dm + b*NV*3;
    float x = 0.f, y = 0.f, z = 0.f, wv = 3.0e38f;
    if (v < NV) {
      x = dmb[v*3+0]; y = dmb[v*3+1]; z = dmb[v*3+2];
      wv = fmaf(x,x, fmaf(y,y, z*z));                // EXACT t.w of r7 metric
    }
    const ushort_t hx = f2bf(x),  hy = f2bf(y),  hz = f2bf(z),  hw = f2bf(wv);
    const ushort_t lx = f2bf(x - bf2f(hx)), ly = f2bf(y - bf2f(hy));
    const ushort_t lz = f2bf(z - bf2f(hz)), lw = f2bf(wv - bf2f(hw));
    U4 F, H;
    F.u[0] = (uint_t)hx | ((uint_t)hy << 16);
    F.u[1] = (uint_t)hz | ((uint_t)hw << 16);
    F.u[2] = (uint_t)lx | ((uint_t)ly << 16);
    F.u[3] = (uint_t)lz | ((uint_t)lw << 16);
    H.u[0] = F.u[0]; H.u[1] = F.u[1]; H.u[2] = 0; H.u[3] = 0;
    *(bf16x8*)(aFF + (size_t)e*8) = F.v;
    *(bf16x8*)(aFH + (size_t)e*8) = H.v;
    vq[e] = make_float4(x, y, z, wv);
  }
}

// ---------------- Kernel 1: MFMA two-phase exact NN (4-way vertex split) + features ----------------
// 2048 blocks x 256 thr = 4 waves; 32 pts/block. Wave w scans vertex quarter w
// (tiles w*40..w*40+39); all 4 waves share the same 32 points (pt = g0 + l31).
// 8192 waves = 32 waves/CU supplied. launch_bounds(256, 6): r12's (256,8) pinned the
// allocator to 64 VGPRs -> SPILL (FETCH 7.4MB->810MB, 786us). Natural alloc is ~60
// (r11 evidence), which itself permits 8 waves/SIMD; cap 85 leaves headroom, no spill.
// Pass-A gmins merge via LDS; pass-B (d2,idx) merge lexicographically over quarters.
__device__ __forceinline__ float min16(const f32x16& d) {
  const float t0 = fminf(fminf(d[0],d[1]),   fminf(d[2],d[3]));
  const float t1 = fminf(fminf(d[4],d[5]),   fminf(d[6],d[7]));
  const float t2 = fminf(fminf(d[8],d[9]),   fminf(d[10],d[11]));
  const float t3 = fminf(fminf(d[12],d[13]), fminf(d[14],d[15]));
  return fminf(fminf(t0,t1), fminf(t2,t3));
}

__global__ __launch_bounds__(256, 6) void k_nnfeat(
    const float* __restrict__ pts, const float* __restrict__ dm,
    const float* __restrict__ cano, const float* __restrict__ lat,
    const ushort_t* __restrict__ aFF, const ushort_t* __restrict__ aFH,
    const float4* __restrict__ vq,
    uint_t* __restrict__ feat, float* __restrict__ base3)
{
  __shared__ float sMin[4][32];
  __shared__ float sDh[4][32];
  __shared__ int   sIh[4][32];

  const int tid = threadIdx.x;
  const int lane = tid & 63, w = tid >> 6;      // w = vertex quarter
  const int l31 = lane & 31, lh = lane >> 5;
  const int g0 = blockIdx.x * 32;
  const int b  = blockIdx.x >> 10;              // 1024 blocks per batch
  const int pt = g0 + l31;

  const float px = pts[pt*3+0], py = pts[pt*3+1], pz = pts[pt*3+2];
  const float p2 = fmaf(px,px, fmaf(py,py, pz*pz));

  // B fragment (per-lane, by lh) — r9-verified encoding
  const float tpx = -2.f*px, tpy = -2.f*py, tpz = -2.f*pz;
  const ushort_t hpx = f2bf(tpx), hpy = f2bf(tpy), hpz = f2bf(tpz);
  const ushort_t lpx = f2bf(tpx - bf2f(hpx));
  const ushort_t lpy = f2bf(tpy - bf2f(hpy));
  const ushort_t lpz = f2bf(tpz - bf2f(hpz));
  U4 Bh, Bl;
  Bh.u[0] = (uint_t)hpx | ((uint_t)hpy << 16);
  Bh.u[1] = (uint_t)hpz | (0x3F80u << 16);      // bf16(1.0)
  Bh.u[2] = Bh.u[0]; Bh.u[3] = Bh.u[1];
  Bl.u[0] = (uint_t)lpx | ((uint_t)lpy << 16);
  Bl.u[1] = (uint_t)lpz;
  Bl.u[2] = 0; Bl.u[3] = 0;
  const bf16x8 bfrag = lh ? Bl.v : Bh.v;

  // this wave's tile range: [w*40, w*40+40)
  const ushort_t* __restrict__ aBase = (lh ? aFH : aFF)
      + (size_t)b * NVP * 8 + (size_t)w * QTILE * 32 * 8;
  const float4*   __restrict__ vqb   = vq + (size_t)b * NVP;
  const int vho = w * QTILE * 32;               // vertex offset of this quarter

  const f32x16 zacc = (f32x16)(0.f);

  // ---- pass A: s-min over this wave's 40 tiles (batched, prefetched) ----
  float gmin = 3.0e38f;
  bf16x8 ap0, ap1, ap2, ap3, an0, an1, an2, an3;
  ap0 = *(const bf16x8*)(aBase + (size_t)(0*32 + l31)*8);
  ap1 = *(const bf16x8*)(aBase + (size_t)(1*32 + l31)*8);
  ap2 = *(const bf16x8*)(aBase + (size_t)(2*32 + l31)*8);
  ap3 = *(const bf16x8*)(aBase + (size_t)(3*32 + l31)*8);
  #pragma unroll 2
  for (int tb = 0; tb < QTILE/4; ++tb) {
    const int t0 = tb*4;
    if (tb + 1 < QTILE/4) {
      an0 = *(const bf16x8*)(aBase + (size_t)((t0+4)*32 + l31)*8);
      an1 = *(const bf16x8*)(aBase + (size_t)((t0+5)*32 + l31)*8);
      an2 = *(const bf16x8*)(aBase + (size_t)((t0+6)*32 + l31)*8);
      an3 = *(const bf16x8*)(aBase + (size_t)((t0+7)*32 + l31)*8);
    }
    const f32x16 d0 = __builtin_amdgcn_mfma_f32_32x32x16_bf16(ap0, bfrag, zacc, 0,0,0);
    const f32x16 d1 = __builtin_amdgcn_mfma_f32_32x32x16_bf16(ap1, bfrag, zacc, 0,0,0);
    const f32x16 d2 = __builtin_amdgcn_mfma_f32_32x32x16_bf16(ap2, bfrag, zacc, 0,0,0);
    const f32x16 d3 = __builtin_amdgcn_mfma_f32_32x32x16_bf16(ap3, bfrag, zacc, 0,0,0);
    const float m0 = min16(d0), m1 = min16(d1), m2 = min16(d2), m3 = min16(d3);
    gmin = fminf(gmin, fminf(fminf(m0,m1), fminf(m2,m3)));
    ap0 = an0; ap1 = an1; ap2 = an2; ap3 = an3;
  }
  gmin = fminf(gmin, __shfl_xor(gmin, 32, 64));  // combine lh halves (rows split)
  if (lane < 32) sMin[w][l31] = gmin;
  __syncthreads();
  const float thr = fminf(fminf(sMin[0][l31], sMin[1][l31]),
                          fminf(sMin[2][l31], sMin[3][l31])) + MARGIN;

  // ---- pass B: exact candidates over this wave's 40 tiles ----
  float bs = 3.4e38f; int bi = 0;
  ap0 = *(const bf16x8*)(aBase + (size_t)(0*32 + l31)*8);
  ap1 = *(const bf16x8*)(aBase + (size_t)(1*32 + l31)*8);
  ap2 = *(const bf16x8*)(aBase + (size_t)(2*32 + l31)*8);
  ap3 = *(const bf16x8*)(aBase + (size_t)(3*32 + l31)*8);
  #pragma unroll 1
  for (int tb = 0; tb < QTILE/4; ++tb) {
    const int t0 = tb*4;
    if (tb + 1 < QTILE/4) {
      an0 = *(const bf16x8*)(aBase + (size_t)((t0+4)*32 + l31)*8);
      an1 = *(const bf16x8*)(aBase + (size_t)((t0+5)*32 + l31)*8);
      an2 = *(const bf16x8*)(aBase + (size_t)((t0+6)*32 + l31)*8);
      an3 = *(const bf16x8*)(aBase + (size_t)((t0+7)*32 + l31)*8);
    }
    f32x16 dd[4];
    dd[0] = __builtin_amdgcn_mfma_f32_32x32x16_bf16(ap0, bfrag, zacc, 0,0,0);
    dd[1] = __builtin_amdgcn_mfma_f32_32x32x16_bf16(ap1, bfrag, zacc, 0,0,0);
    dd[2] = __builtin_amdgcn_mfma_f32_32x32x16_bf16(ap2, bfrag, zacc, 0,0,0);
    dd[3] = __builtin_amdgcn_mfma_f32_32x32x16_bf16(ap3, bfrag, zacc, 0,0,0);
    #pragma unroll
    for (int i = 0; i < 4; ++i) {
      const f32x16 d = dd[i];
      float q4[4];
      q4[0] = fminf(fminf(d[0],d[1]),   fminf(d[2],d[3]));
      q4[1] = fminf(fminf(d[4],d[5]),   fminf(d[6],d[7]));
      q4[2] = fminf(fminf(d[8],d[9]),   fminf(d[10],d[11]));
      q4[3] = fminf(fminf(d[12],d[13]), fminf(d[14],d[15]));
      const float tm = fminf(fminf(q4[0],q4[1]), fminf(q4[2],q4[3]));
      if (tm <= thr) {
        const int t = t0 + i;
        #pragma unroll
        for (int q = 0; q < 4; ++q) {
          if (q4[q] <= thr) {
            #pragma unroll
            for (int rr = 0; rr < 4; ++rr) {
              const int r = q*4 + rr;
              if (d[r] <= thr) {
                const int row = (r & 3) + 8*(r >> 2) + 4*lh;   // C/D row map (verified)
                const int v = vho + t*32 + row;
                const float4 qv = vqb[v];
                const float dot = fmaf(px, qv.x, fmaf(py, qv.y, pz*qv.z));
                float d2 = fmaf(-2.f, dot, p2 + qv.w);          // r7 metric, exact
                d2 = fmaxf(d2, 0.f);
                if (d2 < bs || (d2 == bs && v < bi)) { bs = d2; bi = v; }
              }
            }
          }
        }
      }
    }
    ap0 = an0; ap1 = an1; ap2 = an2; ap3 = an3;
  }
  // merge the lh pair (lexicographic (d2, idx))
  {
    const float ob = __shfl_xor(bs, 32, 64);
    const int   oi = __shfl_xor(bi, 32, 64);
    if (ob < bs || (ob == bs && oi < bi)) { bs = ob; bi = oi; }
  }
  if (lane < 32) { sDh[w][l31] = bs; sIh[w][l31] = bi; }
  __syncthreads();

  // ---- features: 8 wave-uniform slices per point ----
  const int p = tid & 31, slice = tid >> 5;
  const int g = g0 + p;
  float wd = sDh[0][p]; int wi = sIh[0][p];
  #pragma unroll
  for (int qq = 1; qq < 4; ++qq) {
    const float od = sDh[qq][p]; const int oi = sIh[qq][p];
    if (od < wd || (od == wd && oi < wi)) { wd = od; wi = oi; }
  }
  const float* __restrict__ dmb = dm + b * NV * 3;

  const float qx = pts[g*3+0], qy = pts[g*3+1], qz = pts[g*3+2];
  const float wgt = expf(-wd);
  const float sx = (cano[wi*3+0] - dmb[wi*3+0]) * wgt;
  const float sy = (cano[wi*3+1] - dmb[wi*3+1]) * wgt;
  const float sz = (cano[wi*3+2] - dmb[wi*3+2]) * wgt;

  uint_t* __restrict__ fr = feat + (size_t)g * FSTR;

  if (slice == 0) {
    base3[g*3+0] = qx + sx; base3[g*3+1] = qy + sy; base3[g*3+2] = qz + sz;
    fr[0] = packsplit(qx); fr[1] = packsplit(qy); fr[2] = packsplit(qz);
    float s0,c0,s1,c1,s2,c2;
    sincosf(qx,&s0,&c0); sincosf(qy,&s1,&c1); sincosf(qz,&s2,&c2);
    #pragma unroll
    for (int f = 0; f < 3; ++f) {
      const int k = 3 + 6*f;
      fr[k+0]=packsplit(s0); fr[k+1]=packsplit(s1); fr[k+2]=packsplit(s2);
      fr[k+3]=packsplit(c0); fr[k+4]=packsplit(c1); fr[k+5]=packsplit(c2);
      if (f < 2) { dbl_step(s0,c0); dbl_step(s1,c1); dbl_step(s2,c2); }
    }
  } else if (slice == 1) {
    float s0,c0,s1,c1,s2,c2;
    sincosf(qx*8.f,&s0,&c0); sincosf(qy*8.f,&s1,&c1); sincosf(qz*8.f,&s2,&c2);
    #pragma unroll
    for (int f = 3; f < 7; ++f) {
      const int k = 3 + 6*f;
      fr[k+0]=packsplit(s0); fr[k+1]=packsplit(s1); fr[k+2]=packsplit(s2);
      fr[k+3]=packsplit(c0); fr[k+4]=packsplit(c1); fr[k+5]=packsplit(c2);
      if (f < 6) { dbl_step(s0,c0); dbl_step(s1,c1); dbl_step(s2,c2); }
    }
  } else if (slice == 2) {
    float s0,c0,s1,c1,s2,c2;
    sincosf(qx*128.f,&s0,&c0); sincosf(qy*128.f,&s1,&c1); sincosf(qz*128.f,&s2,&c2);
    #pragma unroll
    for (int f = 7; f < 10; ++f) {
      const int k = 3 + 6*f;
      fr[k+0]=packsplit(s0); fr[k+1]=packsplit(s1); fr[k+2]=packsplit(s2);
      fr[k+3]=packsplit(c0); fr[k+4]=packsplit(c1); fr[k+5]=packsplit(c2);
      if (f < 9) { dbl_step(s0,c0); dbl_step(s1,c1); dbl_step(s2,c2); }
    }
  } else if (slice == 3) {
    fr[63]=packsplit(sx); fr[64]=packsplit(sy); fr[65]=packsplit(sz);
    float s0,c0,s1,c1,s2,c2;
    sincosf(sx,&s0,&c0); sincosf(sy,&s1,&c1); sincosf(sz,&s2,&c2);
    #pragma unroll
    for (int f = 0; f < 2; ++f) {
      const int k = 66 + 6*f;
      fr[k+0]=packsplit(s0); fr[k+1]=packsplit(s1); fr[k+2]=packsplit(s2);
      fr[k+3]=packsplit(c0); fr[k+4]=packsplit(c1); fr[k+5]=packsplit(c2);
      if (f < 1) { dbl_step(s0,c0); dbl_step(s1,c1); dbl_step(s2,c2); }
    }
    fr[110] = 0; fr[111] = 0;
  } else {
    // slices 4..7: latent 8 each
    const int j0 = (slice - 4) * 8;
    #pragma unroll
    for (int j = 0; j < 8; ++j) fr[78 + j0 + j] = packsplit(lat[g*LATD + j0 + j]);
  }
}

// ------------- Kernel 2: register-resident MLP (operand-swapped MFMA) — r3 verbatim -------------

__device__ __forceinline__ void zero4(f32x16 (&a)[4]) {
  #pragma unroll
  for (int i = 0; i < 4; ++i) a[i] = (f32x16)(0.f);
}

__device__ __forceinline__ void load_feat_frags(
    const uint_t* __restrict__ fr, bf16x8 (&Xh)[8], bf16x8 (&Xl)[8], int lh)
{
  #pragma unroll
  for (int ks = 0; ks < 7; ++ks) {
    const int k0 = ks*16 + lh*8;
    const uint4 ua = *(const uint4*)(fr + k0);
    const uint4 ub = *(const uint4*)(fr + k0 + 4);
    U4 H, L;
    H.u[0] = (ua.x & 0xffffu) | (ua.y << 16);
    H.u[1] = (ua.z & 0xffffu) | (ua.w << 16);
    H.u[2] = (ub.x & 0xffffu) | (ub.y << 16);
    H.u[3] = (ub.z & 0xffffu) | (ub.w << 16);
    L.u[0] = (ua.x >> 16) | (ua.y & 0xffff0000u);
    L.u[1] = (ua.z >> 16) | (ua.w & 0xffff0000u);
    L.u[2] = (ub.x >> 16) | (ub.y & 0xffff0000u);
    L.u[3] = (ub.z >> 16) | (ub.w & 0xffff0000u);
    Xh[ks] = H.v; Xl[ks] = L.v;
  }
}

__device__ __forceinline__ void load_slab(bf16x8 (&wh)[4], bf16x8 (&wl)[4],
    const ushort_t* __restrict__ Wh, const ushort_t* __restrict__ Wl,
    int ks, int l31, int lh)
{
  const int lo = l31*16 + lh*8;
  #pragma unroll
  for (int tn = 0; tn < 4; ++tn) {
    const int off = (ks*4 + tn)*512 + lo;
    wh[tn] = *(const bf16x8*)(Wh + off);
    wl[tn] = *(const bf16x8*)(Wl + off);
  }
}

__device__ __forceinline__ void mfma_slab(f32x16 (&acc)[4],
    const bf16x8 (&wh)[4], const bf16x8 (&wl)[4],
    const bf16x8& xh, const bf16x8& xl)
{
  #pragma unroll
  for (int tn = 0; tn < 4; ++tn) {
    acc[tn] = __builtin_amdgcn_mfma_f32_32x32x16_bf16(wh[tn], xh, acc[tn], 0,0,0);
    acc[tn] = __builtin_amdgcn_mfma_f32_32x32x16_bf16(wl[tn], xh, acc[tn], 0,0,0);
    acc[tn] = __builtin_amdgcn_mfma_f32_32x32x16_bf16(wh[tn], xl, acc[tn], 0,0,0);
  }
}

template<int NKS, bool TAIL>
__device__ __forceinline__ void run_panel(f32x16 (&acc)[4],
    const ushort_t* __restrict__ Wh, const ushort_t* __restrict__ Wl,
    const ushort_t* __restrict__ WhN, const ushort_t* __restrict__ WlN,
    bf16x8 (&wbh)[2][4], bf16x8 (&wbl)[2][4],
    const bf16x8 (&Xh)[8], const bf16x8 (&Xl)[8], int l31, int lh)
{
  #pragma unroll
  for (int ks = 0; ks < NKS; ++ks) {
    const int b = ks & 1;
    mfma_slab(acc, wbh[b], wbl[b], Xh[ks], Xl[ks]);
    if (ks + 2 < NKS) {
      load_slab(wbh[b], wbl[b], Wh, Wl, ks + 2, l31, lh);
    } else if (TAIL) {
      load_slab(wbh[b], wbl[b], WhN, WlN, ks & 1, l31, lh);
    }
  }
}

__device__ __forceinline__ void bias_relu(f32x16 (&acc)[4],
    const float* __restrict__ bias, int lh)
{
  #pragma unroll
  for (int tn = 0; tn < 4; ++tn)
    #pragma unroll
    for (int b = 0; b < 4; ++b) {
      const float4 b4 = *(const float4*)(bias + tn*32 + 8*b + 4*lh);
      acc[tn][4*b+0] = fmaxf(acc[tn][4*b+0] + b4.x, 0.f);
      acc[tn][4*b+1] = fmaxf(acc[tn][4*b+1] + b4.y, 0.f);
      acc[tn][4*b+2] = fmaxf(acc[tn][4*b+2] + b4.z, 0.f);
      acc[tn][4*b+3] = fmaxf(acc[tn][4*b+3] + b4.w, 0.f);
    }
}

__device__ __forceinline__ void build_frags(const f32x16 (&acc)[4],
    bf16x8 (&Xh)[8], bf16x8 (&Xl)[8], int lh)
{
  #pragma unroll
  for (int ks = 0; ks < 8; ++ks) {
    const int tn = ks >> 1;
    const int rb = 8*(ks & 1);
    const float f0 = acc[tn][rb+0], f1 = acc[tn][rb+1];
    const float f2 = acc[tn][rb+2], f3 = acc[tn][rb+3];
    const float f4 = acc[tn][rb+4], f5 = acc[tn][rb+5];
    const float f6 = acc[tn][rb+6], f7 = acc[tn][rb+7];
    const ushort_t h0=f2bf(f0), h1=f2bf(f1), h2=f2bf(f2), h3=f2bf(f3);
    const ushort_t h4=f2bf(f4), h5=f2bf(f5), h6=f2bf(f6), h7=f2bf(f7);
    const uint_t hA0 = (uint_t)h0 | ((uint_t)h1 << 16);
    const uint_t hA1 = (uint_t)h2 | ((uint_t)h3 << 16);
    const uint_t hB0 = (uint_t)h4 | ((uint_t)h5 << 16);
    const uint_t hB1 = (uint_t)h6 | ((uint_t)h7 << 16);
    const uint_t lA0 = (uint_t)f2bf(f0 - bf2f(h0)) | ((uint_t)f2bf(f1 - bf2f(h1)) << 16);
    const uint_t lA1 = (uint_t)f2bf(f2 - bf2f(h2)) | ((uint_t)f2bf(f3 - bf2f(h3)) << 16);
    const uint_t lB0 = (uint_t)f2bf(f4 - bf2f(h4)) | ((uint_t)f2bf(f5 - bf2f(h5)) << 16);
    const uint_t lB1 = (uint_t)f2bf(f6 - bf2f(h6)) | ((uint_t)f2bf(f7 - bf2f(h7)) << 16);
    const uint_t sh0 = lh ? hA0 : hB0, sh1 = lh ? hA1 : hB1;
    const uint_t sl0 = lh ? lA0 : lB0, sl1 = lh ? lA1 : lB1;
    const uint_t rh0 = __shfl_xor(sh0, 32, 64), rh1 = __shfl_xor(sh1, 32, 64);
    const uint_t rl0 = __shfl_xor(sl0, 32, 64), rl1 = __shfl_xor(sl1, 32, 64);
    U4 H, L;
    H.u[0] = lh ? rh0 : hA0;  H.u[1] = lh ? rh1 : hA1;
    H.u[2] = lh ? hB0 : rh0;  H.u[3] = lh ? hB1 : rh1;
    L.u[0] = lh ? rl0 : lA0;  L.u[1] = lh ? rl1 : lA1;
    L.u[2] = lh ? lB0 : rl0;  L.u[3] = lh ? lB1 : rl1;
    Xh[ks] = H.v; Xl[ks] = L.v;
  }
}

__global__ __launch_bounds__(256, 2) void k_mlp(
    const uint_t* __restrict__ feat, const float* __restrict__ base3,
    const ushort_t* __restrict__ wsWh, const ushort_t* __restrict__ wsWl,
    const float* __restrict__ b0, const float* __restrict__ b1,
    const float* __restrict__ b2, const float* __restrict__ b3,
    const float* __restrict__ b4, const float* __restrict__ b5,
    const float* __restrict__ b6, const float* __restrict__ b7,
    const float* __restrict__ w_out, const float* __restrict__ b_out,
    float* __restrict__ out)
{
  __shared__ __align__(16) float sF[4][32*132];   // per-wave transpose buf
  __shared__ __align__(16) float sB[8*128 + 384 + 4];

  const int tid  = threadIdx.x;
  const int lane = tid & 63, wid = tid >> 6;
  const int l31 = lane & 31, lh = lane >> 5;
  const int p0 = blockIdx.x * 128 + wid * 32;

  {
    const float* bsp[8] = {b0,b1,b2,b3,b4,b5,b6,b7};
    if (tid < 128) {
      #pragma unroll
      for (int l = 0; l < 8; ++l) sB[l*128 + tid] = bsp[l][tid];
    }
    for (int i = tid; i < 384; i += 256) sB[1024 + i] = w_out[i];
    if (tid < 3) sB[1408 + tid] = b_out[tid];
  }

  const uint_t* __restrict__ fr = feat + (size_t)(p0 + l31) * FSTR;

  bf16x8 Xh[8], Xl[8];
  bf16x8 wbh[2][4], wbl[2][4];
  f32x16 acc[4];

  load_slab(wbh[0], wbl[0], wsWh, wsWl, 0, l31, lh);
  load_slab(wbh[1], wbl[1], wsWh, wsWl, 1, l31, lh);
  load_feat_frags(fr, Xh, Xl, lh);
  __syncthreads();

  zero4(acc);
  run_panel<7,true>(acc, wsWh + 0*16384, wsWl + 0*16384,
                         wsWh + 1*16384, wsWl + 1*16384, wbh, wbl, Xh, Xl, l31, lh);
  bias_relu(acc, sB + 0*128, lh);
  build_frags(acc, Xh, Xl, lh);

  zero4(acc);
  run_panel<8,true>(acc, wsWh + 1*16384, wsWl + 1*16384,
                         wsWh + 2*16384, wsWl + 2*16384, wbh, wbl, Xh, Xl, l31, lh);
  bias_relu(acc, sB + 1*128, lh);
  build_frags(acc, Xh, Xl, lh);

  zero4(acc);
  run_panel<8,true>(acc, wsWh + 2*16384, wsWl + 2*16384,
                         wsWh + 3*16384, wsWl + 3*16384, wbh, wbl, Xh, Xl, l31, lh);
  bias_relu(acc, sB + 2*128, lh);
  build_frags(acc, Xh, Xl, lh);

  zero4(acc);
  run_panel<8,true>(acc, wsWh + 3*16384, wsWl + 3*16384,
                         wsWh + 5*16384, wsWl + 5*16384, wbh, wbl, Xh, Xl, l31, lh);
  bias_relu(acc, sB + 3*128, lh);
  build_frags(acc, Xh, Xl, lh);

  zero4(acc);
  run_panel<8,true>(acc, wsWh + 5*16384, wsWl + 5*16384,
                         wsWh + 4*16384, wsWl + 4*16384, wbh, wbl, Xh, Xl, l31, lh);
  load_feat_frags(fr, Xh, Xl, lh);
  run_panel<7,true>(acc, wsWh + 4*16384, wsWl + 4*16384,
                         wsWh + 6*16384, wsWl + 6*16384, wbh, wbl, Xh, Xl, l31, lh);
  bias_relu(acc, sB + 4*128, lh);
  build_frags(acc, Xh, Xl, lh);

  zero4(acc);
  run_panel<8,true>(acc, wsWh + 6*16384, wsWl + 6*16384,
                         wsWh + 7*16384, wsWl + 7*16384, wbh, wbl, Xh, Xl, l31, lh);
  bias_relu(acc, sB + 5*128, lh);
  build_frags(acc, Xh, Xl, lh);

  zero4(acc);
  run_panel<8,true>(acc, wsWh + 7*16384, wsWl + 7*16384,
                         wsWh + 8*16384, wsWl + 8*16384, wbh, wbl, Xh, Xl, l31, lh);
  bias_relu(acc, sB + 6*128, lh);
  build_frags(acc, Xh, Xl, lh);

  zero4(acc);
  run_panel<8,false>(acc, wsWh + 8*16384, wsWl + 8*16384,
                          (const ushort_t*)0, (const ushort_t*)0, wbh, wbl, Xh, Xl, l31, lh);

  float* __restrict__ sFw = &sF[wid][0];
  #pragma unroll
  for (int tn = 0; tn < 4; ++tn)
    #pragma unroll
    for (int b = 0; b < 4; ++b) {
      const int n0 = tn*32 + 8*b + 4*lh;
      const float4 bv = *(const float4*)(sB + 7*128 + n0);
      const float v0 = acc[tn][4*b+0] + bv.x;
      const float v1 = acc[tn][4*b+1] + bv.y;
      const float v2 = acc[tn][4*b+2] + bv.z;
      const float v3 = acc[tn][4*b+3] + bv.w;
      *(float4*)(sFw + l31*132 + n0) = make_float4(v0, v1, v2, v3);
      acc[tn][4*b+0] = fmaxf(v0, 0.f);
      acc[tn][4*b+1] = fmaxf(v1, 0.f);
      acc[tn][4*b+2] = fmaxf(v2, 0.f);
      acc[tn][4*b+3] = fmaxf(v3, 0.f);
    }

  asm volatile("s_waitcnt lgkmcnt(0)" ::: "memory");
  __builtin_amdgcn_sched_barrier(0);

  float* __restrict__ out1 = out + (size_t)NPTS * 3;
  #pragma unroll
  for (int i = 0; i < 16; ++i) {
    const int idx = i*64 + lane;
    const int p = idx >> 5, q = idx & 31;
    const float4 v = *(const float4*)(sFw + p*132 + q*4);
    *(float4*)(out1 + (size_t)(p0 + p)*128 + q*4) = v;
  }

  float dotc[3];
  #pragma unroll
  for (int c = 0; c < 3; ++c) {
    float a = 0.f;
    #pragma unroll
    for (int tn = 0; tn < 4; ++tn)
      #pragma unroll
      for (int b = 0; b < 4; ++b) {
        const int n0 = tn*32 + 8*b + 4*lh;
        const float4 w4 = *(const float4*)(sB + 1024 + c*128 + n0);
        a = fmaf(acc[tn][4*b+0], w4.x, a);
        a = fmaf(acc[tn][4*b+1], w4.y, a);
        a = fmaf(acc[tn][4*b+2], w4.z, a);
        a = fmaf(acc[tn][4*b+3], w4.w, a);
      }
    a += __shfl_xor(a, 32, 64);
    dotc[c] = a;
  }
  if (lh == 0) {
    const int g = p0 + l31;
    #pragma unroll
    for (int c = 0; c < 3; ++c)
      out[g*3 + c] = base3[g*3 + c] + dotc[c] + sB[1408 + c];
  }
}

extern "C" void kernel_launch(void* const* d_in, const int* in_sizes, int n_in,
                              void* d_out, int out_size, void* d_ws, size_t ws_size,
                              hipStream_t stream)
{
  const float* pts  = (const float*)d_in[0];
  const float* dm   = (const float*)d_in[1];
  const float* cano = (const float*)d_in[2];
  const float* lat  = (const float*)d_in[3];
  const float* w[8]; const float* b[8];
  for (int i = 0; i < 8; ++i) {
    w[i] = (const float*)d_in[4 + 2*i];
    b[i] = (const float*)d_in[5 + 2*i];
  }
  const float* w_out = (const float*)d_in[20];
  const float* b_out = (const float*)d_in[21];
  float* out = (float*)d_out;

  // ws: feat [NPTS][112] uint (29.36MB) | base3 (786KB) | wsWh (288KB) | wsWl (288KB)
  //     | aFF 2*5120*16B (160KB) | aFH (160KB) | vq 2*5120*16B (160KB)
  uint_t*   feat  = (uint_t*)d_ws;
  float*    base3 = (float*)((char*)d_ws + (size_t)NPTS*FSTR*4);
  ushort_t* wsWh  = (ushort_t*)((char*)base3 + (size_t)NPTS*3*4);
  ushort_t* wsWl  = wsWh + 147456;
  ushort_t* aFF   = wsWl + 147456;
  ushort_t* aFH   = aFF + 2*NVP*8;
  float4*   vq    = (float4*)(aFH + 2*NVP*8);

  k_prep<<<576, 256, 0, stream>>>(dm,
      w[0],w[1],w[2],w[3],w[4],w[5],w[6],w[7], wsWh, wsWl, aFF, aFH, vq);
  k_nnfeat<<<2048, 256, 0, stream>>>(pts, dm, cano, lat, aFF, aFH, vq, feat, base3);
  k_mlp<<<NPTS/128, 256, 0, stream>>>(feat, base3, wsWh, wsWl,
      b[0],b[1],b[2],b[3],b[4],b[5],b[6],b[7], w_out, b_out, out);
}

// Round 14
// 231.619 us; speedup vs baseline: 3.3921x; 2.6242x over previous
//
#include <hip/hip_runtime.h>
#include <math.h>

typedef unsigned short ushort_t;
typedef unsigned int   uint_t;
typedef __attribute__((ext_vector_type(8)))  short bf16x8;
typedef __attribute__((ext_vector_type(16))) float f32x16;

#define NPTS   65536   // B*P
#define NV     5023
#define NVP    5120    // padded to 160 tiles of 32
#define NTILE  160
#define QTILE  40      // tiles per wave-quarter (4-way vertex split)
#define LATD   32
#define KF     110
#define FSTR   112     // feat row stride (uints)
#define MARGIN 1.5e-2f // >= 2*mfma_err(~2.5e-3) + exact-path err; 3x headroom

union U4 { uint_t u[4]; bf16x8 v; };

__device__ __forceinline__ ushort_t f2bf(float f) {
  union { float f; unsigned u; } x; x.f = f;
  unsigned r = x.u + 0x7fffu + ((x.u >> 16) & 1u);   // RNE
  return (ushort_t)(r >> 16);
}
__device__ __forceinline__ float bf2f(ushort_t u) {
  union { unsigned u; float f; } x; x.u = ((unsigned)u) << 16;
  return x.f;
}
__device__ __forceinline__ uint_t packsplit(float v) {
  const ushort_t h = f2bf(v);
  const ushort_t l = f2bf(v - bf2f(h));
  return (uint_t)h | ((uint_t)l << 16);
}

// exact double-angle step: (sin a, cos a) -> (sin 2a, cos 2a)  [r5-verified]
__device__ __forceinline__ void dbl_step(float& s, float& c) {
  const float t = s * c;
  const float cn = fmaf(-2.f * s, s, 1.f);
  s = t + t;
  c = cn;
}

// ---------------- Kernel 0: prep (weights + vertex MFMA-fragments) — r9 verbatim ----------------
__global__ __launch_bounds__(256) void k_prep(
    const float* __restrict__ dm,
    const float* __restrict__ w0, const float* __restrict__ w1,
    const float* __restrict__ w2, const float* __restrict__ w3,
    const float* __restrict__ w4, const float* __restrict__ w5,
    const float* __restrict__ w6, const float* __restrict__ w7,
    ushort_t* __restrict__ wsWh, ushort_t* __restrict__ wsWl,
    ushort_t* __restrict__ aFF, ushort_t* __restrict__ aFH,
    float4* __restrict__ vq)
{
  const int e = blockIdx.x * 256 + threadIdx.x;    // 576*256 = 147456 exactly
  {
    const int p = e >> 14, local = e & 16383;
    const int j   = local & 7;
    const int lh  = (local >> 3) & 1;
    const int l31 = (local >> 4) & 31;
    const int tn  = (local >> 9) & 3;
    const int ks  = (local >> 11) & 7;
    const int n = tn*32 + l31;
    const int k = ks*16 + lh*8 + j;
    float v;
    if (p == 0)      v = (k < KF) ? w0[n*110 + k] : 0.f;
    else if (p == 1) v = w1[n*128 + k];
    else if (p == 2) v = w2[n*128 + k];
    else if (p == 3) v = w3[n*128 + k];
    else if (p == 4) v = (k < KF) ? w4[n*238 + k] : 0.f;
    else if (p == 5) v = w4[n*238 + KF + k];
    else if (p == 6) v = w5[n*128 + k];
    else if (p == 7) v = w6[n*128 + k];
    else             v = w7[n*128 + k];
    const ushort_t h = f2bf(v);
    wsWh[e] = h;
    wsWl[e] = f2bf(v - bf2f(h));
  }
  if (e < 2*NVP) {
    const int b = (e >= NVP) ? 1 : 0;
    const int v = e - b*NVP;
    const float* __restrict__ dmb = dm + b*NV*3;
    float x = 0.f, y = 0.f, z = 0.f, wv = 3.0e38f;
    if (v < NV) {
      x = dmb[v*3+0]; y = dmb[v*3+1]; z = dmb[v*3+2];
      wv = fmaf(x,x, fmaf(y,y, z*z));                // EXACT t.w of r7 metric
    }
    const ushort_t hx = f2bf(x),  hy = f2bf(y),  hz = f2bf(z),  hw = f2bf(wv);
    const ushort_t lx = f2bf(x - bf2f(hx)), ly = f2bf(y - bf2f(hy));
    const ushort_t lz = f2bf(z - bf2f(hz)), lw = f2bf(wv - bf2f(hw));
    U4 F, H;
    F.u[0] = (uint_t)hx | ((uint_t)hy << 16);
    F.u[1] = (uint_t)hz | ((uint_t)hw << 16);
    F.u[2] = (uint_t)lx | ((uint_t)ly << 16);
    F.u[3] = (uint_t)lz | ((uint_t)lw << 16);
    H.u[0] = F.u[0]; H.u[1] = F.u[1]; H.u[2] = 0; H.u[3] = 0;
    *(bf16x8*)(aFF + (size_t)e*8) = F.v;
    *(bf16x8*)(aFH + (size_t)e*8) = H.v;
    vq[e] = make_float4(x, y, z, wv);
  }
}

// ---------------- Kernel 1: MFMA two-phase exact NN (4-way vertex split) + features ----------------
// 2048 blocks x 256 thr = 4 waves; 32 pts/block. Wave w scans vertex quarter w
// (tiles w*40..w*40+39); all 4 waves share the same 32 points (pt = g0 + l31).
// 8192 waves = 32 waves/CU supplied. launch_bounds(256, 4): hard pins >=6 (r12: 8,
// r13: 6) made the allocator SPILL (FETCH 7.4MB -> 420-810MB) despite caps above the
// natural ~60-VGPR allocation (r11 evidence at (256,4)). The 2nd arg is a compile-time
// floor, not the runtime ceiling: at ~60 VGPR, 8 waves/SIMD are reachable at runtime
// and the grid supplies them. Rule learned: min-waves pins <= 4 only on this code.
// Pass-A gmins merge via LDS; pass-B (d2,idx) merge lexicographically over quarters.
__device__ __forceinline__ float min16(const f32x16& d) {
  const float t0 = fminf(fminf(d[0],d[1]),   fminf(d[2],d[3]));
  const float t1 = fminf(fminf(d[4],d[5]),   fminf(d[6],d[7]));
  const float t2 = fminf(fminf(d[8],d[9]),   fminf(d[10],d[11]));
  const float t3 = fminf(fminf(d[12],d[13]), fminf(d[14],d[15]));
  return fminf(fminf(t0,t1), fminf(t2,t3));
}

__global__ __launch_bounds__(256, 4) void k_nnfeat(
    const float* __restrict__ pts, const float* __restrict__ dm,
    const float* __restrict__ cano, const float* __restrict__ lat,
    const ushort_t* __restrict__ aFF, const ushort_t* __restrict__ aFH,
    const float4* __restrict__ vq,
    uint_t* __restrict__ feat, float* __restrict__ base3)
{
  __shared__ float sMin[4][32];
  __shared__ float sDh[4][32];
  __shared__ int   sIh[4][32];

  const int tid = threadIdx.x;
  const int lane = tid & 63, w = tid >> 6;      // w = vertex quarter
  const int l31 = lane & 31, lh = lane >> 5;
  const int g0 = blockIdx.x * 32;
  const int b  = blockIdx.x >> 10;              // 1024 blocks per batch
  const int pt = g0 + l31;

  const float px = pts[pt*3+0], py = pts[pt*3+1], pz = pts[pt*3+2];
  const float p2 = fmaf(px,px, fmaf(py,py, pz*pz));

  // B fragment (per-lane, by lh) — r9-verified encoding
  const float tpx = -2.f*px, tpy = -2.f*py, tpz = -2.f*pz;
  const ushort_t hpx = f2bf(tpx), hpy = f2bf(tpy), hpz = f2bf(tpz);
  const ushort_t lpx = f2bf(tpx - bf2f(hpx));
  const ushort_t lpy = f2bf(tpy - bf2f(hpy));
  const ushort_t lpz = f2bf(tpz - bf2f(hpz));
  U4 Bh, Bl;
  Bh.u[0] = (uint_t)hpx | ((uint_t)hpy << 16);
  Bh.u[1] = (uint_t)hpz | (0x3F80u << 16);      // bf16(1.0)
  Bh.u[2] = Bh.u[0]; Bh.u[3] = Bh.u[1];
  Bl.u[0] = (uint_t)lpx | ((uint_t)lpy << 16);
  Bl.u[1] = (uint_t)lpz;
  Bl.u[2] = 0; Bl.u[3] = 0;
  const bf16x8 bfrag = lh ? Bl.v : Bh.v;

  // this wave's tile range: [w*40, w*40+40)
  const ushort_t* __restrict__ aBase = (lh ? aFH : aFF)
      + (size_t)b * NVP * 8 + (size_t)w * QTILE * 32 * 8;
  const float4*   __restrict__ vqb   = vq + (size_t)b * NVP;
  const int vho = w * QTILE * 32;               // vertex offset of this quarter

  const f32x16 zacc = (f32x16)(0.f);

  // ---- pass A: s-min over this wave's 40 tiles (batched, prefetched) ----
  float gmin = 3.0e38f;
  bf16x8 ap0, ap1, ap2, ap3, an0, an1, an2, an3;
  ap0 = *(const bf16x8*)(aBase + (size_t)(0*32 + l31)*8);
  ap1 = *(const bf16x8*)(aBase + (size_t)(1*32 + l31)*8);
  ap2 = *(const bf16x8*)(aBase + (size_t)(2*32 + l31)*8);
  ap3 = *(const bf16x8*)(aBase + (size_t)(3*32 + l31)*8);
  #pragma unroll 2
  for (int tb = 0; tb < QTILE/4; ++tb) {
    const int t0 = tb*4;
    if (tb + 1 < QTILE/4) {
      an0 = *(const bf16x8*)(aBase + (size_t)((t0+4)*32 + l31)*8);
      an1 = *(const bf16x8*)(aBase + (size_t)((t0+5)*32 + l31)*8);
      an2 = *(const bf16x8*)(aBase + (size_t)((t0+6)*32 + l31)*8);
      an3 = *(const bf16x8*)(aBase + (size_t)((t0+7)*32 + l31)*8);
    }
    const f32x16 d0 = __builtin_amdgcn_mfma_f32_32x32x16_bf16(ap0, bfrag, zacc, 0,0,0);
    const f32x16 d1 = __builtin_amdgcn_mfma_f32_32x32x16_bf16(ap1, bfrag, zacc, 0,0,0);
    const f32x16 d2 = __builtin_amdgcn_mfma_f32_32x32x16_bf16(ap2, bfrag, zacc, 0,0,0);
    const f32x16 d3 = __builtin_amdgcn_mfma_f32_32x32x16_bf16(ap3, bfrag, zacc, 0,0,0);
    const float m0 = min16(d0), m1 = min16(d1), m2 = min16(d2), m3 = min16(d3);
    gmin = fminf(gmin, fminf(fminf(m0,m1), fminf(m2,m3)));
    ap0 = an0; ap1 = an1; ap2 = an2; ap3 = an3;
  }
  gmin = fminf(gmin, __shfl_xor(gmin, 32, 64));  // combine lh halves (rows split)
  if (lane < 32) sMin[w][l31] = gmin;
  __syncthreads();
  const float thr = fminf(fminf(sMin[0][l31], sMin[1][l31]),
                          fminf(sMin[2][l31], sMin[3][l31])) + MARGIN;

  // ---- pass B: exact candidates over this wave's 40 tiles ----
  float bs = 3.4e38f; int bi = 0;
  ap0 = *(const bf16x8*)(aBase + (size_t)(0*32 + l31)*8);
  ap1 = *(const bf16x8*)(aBase + (size_t)(1*32 + l31)*8);
  ap2 = *(const bf16x8*)(aBase + (size_t)(2*32 + l31)*8);
  ap3 = *(const bf16x8*)(aBase + (size_t)(3*32 + l31)*8);
  #pragma unroll 1
  for (int tb = 0; tb < QTILE/4; ++tb) {
    const int t0 = tb*4;
    if (tb + 1 < QTILE/4) {
      an0 = *(const bf16x8*)(aBase + (size_t)((t0+4)*32 + l31)*8);
      an1 = *(const bf16x8*)(aBase + (size_t)((t0+5)*32 + l31)*8);
      an2 = *(const bf16x8*)(aBase + (size_t)((t0+6)*32 + l31)*8);
      an3 = *(const bf16x8*)(aBase + (size_t)((t0+7)*32 + l31)*8);
    }
    f32x16 dd[4];
    dd[0] = __builtin_amdgcn_mfma_f32_32x32x16_bf16(ap0, bfrag, zacc, 0,0,0);
    dd[1] = __builtin_amdgcn_mfma_f32_32x32x16_bf16(ap1, bfrag, zacc, 0,0,0);
    dd[2] = __builtin_amdgcn_mfma_f32_32x32x16_bf16(ap2, bfrag, zacc, 0,0,0);
    dd[3] = __builtin_amdgcn_mfma_f32_32x32x16_bf16(ap3, bfrag, zacc, 0,0,0);
    #pragma unroll
    for (int i = 0; i < 4; ++i) {
      const f32x16 d = dd[i];
      float q4[4];
      q4[0] = fminf(fminf(d[0],d[1]),   fminf(d[2],d[3]));
      q4[1] = fminf(fminf(d[4],d[5]),   fminf(d[6],d[7]));
      q4[2] = fminf(fminf(d[8],d[9]),   fminf(d[10],d[11]));
      q4[3] = fminf(fminf(d[12],d[13]), fminf(d[14],d[15]));
      const float tm = fminf(fminf(q4[0],q4[1]), fminf(q4[2],q4[3]));
      if (tm <= thr) {
        const int t = t0 + i;
        #pragma unroll
        for (int q = 0; q < 4; ++q) {
          if (q4[q] <= thr) {
            #pragma unroll
            for (int rr = 0; rr < 4; ++rr) {
              const int r = q*4 + rr;
              if (d[r] <= thr) {
                const int row = (r & 3) + 8*(r >> 2) + 4*lh;   // C/D row map (verified)
                const int v = vho + t*32 + row;
                const float4 qv = vqb[v];
                const float dot = fmaf(px, qv.x, fmaf(py, qv.y, pz*qv.z));
                float d2 = fmaf(-2.f, dot, p2 + qv.w);          // r7 metric, exact
                d2 = fmaxf(d2, 0.f);
                if (d2 < bs || (d2 == bs && v < bi)) { bs = d2; bi = v; }
              }
            }
          }
        }
      }
    }
    ap0 = an0; ap1 = an1; ap2 = an2; ap3 = an3;
  }
  // merge the lh pair (lexicographic (d2, idx))
  {
    const float ob = __shfl_xor(bs, 32, 64);
    const int   oi = __shfl_xor(bi, 32, 64);
    if (ob < bs || (ob == bs && oi < bi)) { bs = ob; bi = oi; }
  }
  if (lane < 32) { sDh[w][l31] = bs; sIh[w][l31] = bi; }
  __syncthreads();

  // ---- features: 8 wave-uniform slices per point ----
  const int p = tid & 31, slice = tid >> 5;
  const int g = g0 + p;
  float wd = sDh[0][p]; int wi = sIh[0][p];
  #pragma unroll
  for (int qq = 1; qq < 4; ++qq) {
    const float od = sDh[qq][p]; const int oi = sIh[qq][p];
    if (od < wd || (od == wd && oi < wi)) { wd = od; wi = oi; }
  }
  const float* __restrict__ dmb = dm + b * NV * 3;

  const float qx = pts[g*3+0], qy = pts[g*3+1], qz = pts[g*3+2];
  const float wgt = expf(-wd);
  const float sx = (cano[wi*3+0] - dmb[wi*3+0]) * wgt;
  const float sy = (cano[wi*3+1] - dmb[wi*3+1]) * wgt;
  const float sz = (cano[wi*3+2] - dmb[wi*3+2]) * wgt;

  uint_t* __restrict__ fr = feat + (size_t)g * FSTR;

  if (slice == 0) {
    base3[g*3+0] = qx + sx; base3[g*3+1] = qy + sy; base3[g*3+2] = qz + sz;
    fr[0] = packsplit(qx); fr[1] = packsplit(qy); fr[2] = packsplit(qz);
    float s0,c0,s1,c1,s2,c2;
    sincosf(qx,&s0,&c0); sincosf(qy,&s1,&c1); sincosf(qz,&s2,&c2);
    #pragma unroll
    for (int f = 0; f < 3; ++f) {
      const int k = 3 + 6*f;
      fr[k+0]=packsplit(s0); fr[k+1]=packsplit(s1); fr[k+2]=packsplit(s2);
      fr[k+3]=packsplit(c0); fr[k+4]=packsplit(c1); fr[k+5]=packsplit(c2);
      if (f < 2) { dbl_step(s0,c0); dbl_step(s1,c1); dbl_step(s2,c2); }
    }
  } else if (slice == 1) {
    float s0,c0,s1,c1,s2,c2;
    sincosf(qx*8.f,&s0,&c0); sincosf(qy*8.f,&s1,&c1); sincosf(qz*8.f,&s2,&c2);
    #pragma unroll
    for (int f = 3; f < 7; ++f) {
      const int k = 3 + 6*f;
      fr[k+0]=packsplit(s0); fr[k+1]=packsplit(s1); fr[k+2]=packsplit(s2);
      fr[k+3]=packsplit(c0); fr[k+4]=packsplit(c1); fr[k+5]=packsplit(c2);
      if (f < 6) { dbl_step(s0,c0); dbl_step(s1,c1); dbl_step(s2,c2); }
    }
  } else if (slice == 2) {
    float s0,c0,s1,c1,s2,c2;
    sincosf(qx*128.f,&s0,&c0); sincosf(qy*128.f,&s1,&c1); sincosf(qz*128.f,&s2,&c2);
    #pragma unroll
    for (int f = 7; f < 10; ++f) {
      const int k = 3 + 6*f;
      fr[k+0]=packsplit(s0); fr[k+1]=packsplit(s1); fr[k+2]=packsplit(s2);
      fr[k+3]=packsplit(c0); fr[k+4]=packsplit(c1); fr[k+5]=packsplit(c2);
      if (f < 9) { dbl_step(s0,c0); dbl_step(s1,c1); dbl_step(s2,c2); }
    }
  } else if (slice == 3) {
    fr[63]=packsplit(sx); fr[64]=packsplit(sy); fr[65]=packsplit(sz);
    float s0,c0,s1,c1,s2,c2;
    sincosf(sx,&s0,&c0); sincosf(sy,&s1,&c1); sincosf(sz,&s2,&c2);
    #pragma unroll
    for (int f = 0; f < 2; ++f) {
      const int k = 66 + 6*f;
      fr[k+0]=packsplit(s0); fr[k+1]=packsplit(s1); fr[k+2]=packsplit(s2);
      fr[k+3]=packsplit(c0); fr[k+4]=packsplit(c1); fr[k+5]=packsplit(c2);
      if (f < 1) { dbl_step(s0,c0); dbl_step(s1,c1); dbl_step(s2,c2); }
    }
    fr[110] = 0; fr[111] = 0;
  } else {
    // slices 4..7: latent 8 each
    const int j0 = (slice - 4) * 8;
    #pragma unroll
    for (int j = 0; j < 8; ++j) fr[78 + j0 + j] = packsplit(lat[g*LATD + j0 + j]);
  }
}

// ------------- Kernel 2: register-resident MLP (operand-swapped MFMA) — r3 verbatim -------------

__device__ __forceinline__ void zero4(f32x16 (&a)[4]) {
  #pragma unroll
  for (int i = 0; i < 4; ++i) a[i] = (f32x16)(0.f);
}

__device__ __forceinline__ void load_feat_frags(
    const uint_t* __restrict__ fr, bf16x8 (&Xh)[8], bf16x8 (&Xl)[8], int lh)
{
  #pragma unroll
  for (int ks = 0; ks < 7; ++ks) {
    const int k0 = ks*16 + lh*8;
    const uint4 ua = *(const uint4*)(fr + k0);
    const uint4 ub = *(const uint4*)(fr + k0 + 4);
    U4 H, L;
    H.u[0] = (ua.x & 0xffffu) | (ua.y << 16);
    H.u[1] = (ua.z & 0xffffu) | (ua.w << 16);
    H.u[2] = (ub.x & 0xffffu) | (ub.y << 16);
    H.u[3] = (ub.z & 0xffffu) | (ub.w << 16);
    L.u[0] = (ua.x >> 16) | (ua.y & 0xffff0000u);
    L.u[1] = (ua.z >> 16) | (ua.w & 0xffff0000u);
    L.u[2] = (ub.x >> 16) | (ub.y & 0xffff0000u);
    L.u[3] = (ub.z >> 16) | (ub.w & 0xffff0000u);
    Xh[ks] = H.v; Xl[ks] = L.v;
  }
}

__device__ __forceinline__ void load_slab(bf16x8 (&wh)[4], bf16x8 (&wl)[4],
    const ushort_t* __restrict__ Wh, const ushort_t* __restrict__ Wl,
    int ks, int l31, int lh)
{
  const int lo = l31*16 + lh*8;
  #pragma unroll
  for (int tn = 0; tn < 4; ++tn) {
    const int off = (ks*4 + tn)*512 + lo;
    wh[tn] = *(const bf16x8*)(Wh + off);
    wl[tn] = *(const bf16x8*)(Wl + off);
  }
}

__device__ __forceinline__ void mfma_slab(f32x16 (&acc)[4],
    const bf16x8 (&wh)[4], const bf16x8 (&wl)[4],
    const bf16x8& xh, const bf16x8& xl)
{
  #pragma unroll
  for (int tn = 0; tn < 4; ++tn) {
    acc[tn] = __builtin_amdgcn_mfma_f32_32x32x16_bf16(wh[tn], xh, acc[tn], 0,0,0);
    acc[tn] = __builtin_amdgcn_mfma_f32_32x32x16_bf16(wl[tn], xh, acc[tn], 0,0,0);
    acc[tn] = __builtin_amdgcn_mfma_f32_32x32x16_bf16(wh[tn], xl, acc[tn], 0,0,0);
  }
}

template<int NKS, bool TAIL>
__device__ __forceinline__ void run_panel(f32x16 (&acc)[4],
    const ushort_t* __restrict__ Wh, const ushort_t* __restrict__ Wl,
    const ushort_t* __restrict__ WhN, const ushort_t* __restrict__ WlN,
    bf16x8 (&wbh)[2][4], bf16x8 (&wbl)[2][4],
    const bf16x8 (&Xh)[8], const bf16x8 (&Xl)[8], int l31, int lh)
{
  #pragma unroll
  for (int ks = 0; ks < NKS; ++ks) {
    const int b = ks & 1;
    mfma_slab(acc, wbh[b], wbl[b], Xh[ks], Xl[ks]);
    if (ks + 2 < NKS) {
      load_slab(wbh[b], wbl[b], Wh, Wl, ks + 2, l31, lh);
    } else if (TAIL) {
      load_slab(wbh[b], wbl[b], WhN, WlN, ks & 1, l31, lh);
    }
  }
}

__device__ __forceinline__ void bias_relu(f32x16 (&acc)[4],
    const float* __restrict__ bias, int lh)
{
  #pragma unroll
  for (int tn = 0; tn < 4; ++tn)
    #pragma unroll
    for (int b = 0; b < 4; ++b) {
      const float4 b4 = *(const float4*)(bias + tn*32 + 8*b + 4*lh);
      acc[tn][4*b+0] = fmaxf(acc[tn][4*b+0] + b4.x, 0.f);
      acc[tn][4*b+1] = fmaxf(acc[tn][4*b+1] + b4.y, 0.f);
      acc[tn][4*b+2] = fmaxf(acc[tn][4*b+2] + b4.z, 0.f);
      acc[tn][4*b+3] = fmaxf(acc[tn][4*b+3] + b4.w, 0.f);
    }
}

__device__ __forceinline__ void build_frags(const f32x16 (&acc)[4],
    bf16x8 (&Xh)[8], bf16x8 (&Xl)[8], int lh)
{
  #pragma unroll
  for (int ks = 0; ks < 8; ++ks) {
    const int tn = ks >> 1;
    const int rb = 8*(ks & 1);
    const float f0 = acc[tn][rb+0], f1 = acc[tn][rb+1];
    const float f2 = acc[tn][rb+2], f3 = acc[tn][rb+3];
    const float f4 = acc[tn][rb+4], f5 = acc[tn][rb+5];
    const float f6 = acc[tn][rb+6], f7 = acc[tn][rb+7];
    const ushort_t h0=f2bf(f0), h1=f2bf(f1), h2=f2bf(f2), h3=f2bf(f3);
    const ushort_t h4=f2bf(f4), h5=f2bf(f5), h6=f2bf(f6), h7=f2bf(f7);
    const uint_t hA0 = (uint_t)h0 | ((uint_t)h1 << 16);
    const uint_t hA1 = (uint_t)h2 | ((uint_t)h3 << 16);
    const uint_t hB0 = (uint_t)h4 | ((uint_t)h5 << 16);
    const uint_t hB1 = (uint_t)h6 | ((uint_t)h7 << 16);
    const uint_t lA0 = (uint_t)f2bf(f0 - bf2f(h0)) | ((uint_t)f2bf(f1 - bf2f(h1)) << 16);
    const uint_t lA1 = (uint_t)f2bf(f2 - bf2f(h2)) | ((uint_t)f2bf(f3 - bf2f(h3)) << 16);
    const uint_t lB0 = (uint_t)f2bf(f4 - bf2f(h4)) | ((uint_t)f2bf(f5 - bf2f(h5)) << 16);
    const uint_t lB1 = (uint_t)f2bf(f6 - bf2f(h6)) | ((uint_t)f2bf(f7 - bf2f(h7)) << 16);
    const uint_t sh0 = lh ? hA0 : hB0, sh1 = lh ? hA1 : hB1;
    const uint_t sl0 = lh ? lA0 : lB0, sl1 = lh ? lA1 : lB1;
    const uint_t rh0 = __shfl_xor(sh0, 32, 64), rh1 = __shfl_xor(sh1, 32, 64);
    const uint_t rl0 = __shfl_xor(sl0, 32, 64), rl1 = __shfl_xor(sl1, 32, 64);
    U4 H, L;
    H.u[0] = lh ? rh0 : hA0;  H.u[1] = lh ? rh1 : hA1;
    H.u[2] = lh ? hB0 : rh0;  H.u[3] = lh ? hB1 : rh1;
    L.u[0] = lh ? rl0 : lA0;  L.u[1] = lh ? rl1 : lA1;
    L.u[2] = lh ? lB0 : rl0;  L.u[3] = lh ? lB1 : rl1;
    Xh[ks] = H.v; Xl[ks] = L.v;
  }
}

__global__ __launch_bounds__(256, 2) void k_mlp(
    const uint_t* __restrict__ feat, const float* __restrict__ base3,
    const ushort_t* __restrict__ wsWh, const ushort_t* __restrict__ wsWl,
    const float* __restrict__ b0, const float* __restrict__ b1,
    const float* __restrict__ b2, const float* __restrict__ b3,
    const float* __restrict__ b4, const float* __restrict__ b5,
    const float* __restrict__ b6, const float* __restrict__ b7,
    const float* __restrict__ w_out, const float* __restrict__ b_out,
    float* __restrict__ out)
{
  __shared__ __align__(16) float sF[4][32*132];   // per-wave transpose buf
  __shared__ __align__(16) float sB[8*128 + 384 + 4];

  const int tid  = threadIdx.x;
  const int lane = tid & 63, wid = tid >> 6;
  const int l31 = lane & 31, lh = lane >> 5;
  const int p0 = blockIdx.x * 128 + wid * 32;

  {
    const float* bsp[8] = {b0,b1,b2,b3,b4,b5,b6,b7};
    if (tid < 128) {
      #pragma unroll
      for (int l = 0; l < 8; ++l) sB[l*128 + tid] = bsp[l][tid];
    }
    for (int i = tid; i < 384; i += 256) sB[1024 + i] = w_out[i];
    if (tid < 3) sB[1408 + tid] = b_out[tid];
  }

  const uint_t* __restrict__ fr = feat + (size_t)(p0 + l31) * FSTR;

  bf16x8 Xh[8], Xl[8];
  bf16x8 wbh[2][4], wbl[2][4];
  f32x16 acc[4];

  load_slab(wbh[0], wbl[0], wsWh, wsWl, 0, l31, lh);
  load_slab(wbh[1], wbl[1], wsWh, wsWl, 1, l31, lh);
  load_feat_frags(fr, Xh, Xl, lh);
  __syncthreads();

  zero4(acc);
  run_panel<7,true>(acc, wsWh + 0*16384, wsWl + 0*16384,
                         wsWh + 1*16384, wsWl + 1*16384, wbh, wbl, Xh, Xl, l31, lh);
  bias_relu(acc, sB + 0*128, lh);
  build_frags(acc, Xh, Xl, lh);

  zero4(acc);
  run_panel<8,true>(acc, wsWh + 1*16384, wsWl + 1*16384,
                         wsWh + 2*16384, wsWl + 2*16384, wbh, wbl, Xh, Xl, l31, lh);
  bias_relu(acc, sB + 1*128, lh);
  build_frags(acc, Xh, Xl, lh);

  zero4(acc);
  run_panel<8,true>(acc, wsWh + 2*16384, wsWl + 2*16384,
                         wsWh + 3*16384, wsWl + 3*16384, wbh, wbl, Xh, Xl, l31, lh);
  bias_relu(acc, sB + 2*128, lh);
  build_frags(acc, Xh, Xl, lh);

  zero4(acc);
  run_panel<8,true>(acc, wsWh + 3*16384, wsWl + 3*16384,
                         wsWh + 5*16384, wsWl + 5*16384, wbh, wbl, Xh, Xl, l31, lh);
  bias_relu(acc, sB + 3*128, lh);
  build_frags(acc, Xh, Xl, lh);

  zero4(acc);
  run_panel<8,true>(acc, wsWh + 5*16384, wsWl + 5*16384,
                         wsWh + 4*16384, wsWl + 4*16384, wbh, wbl, Xh, Xl, l31, lh);
  load_feat_frags(fr, Xh, Xl, lh);
  run_panel<7,true>(acc, wsWh + 4*16384, wsWl + 4*16384,
                         wsWh + 6*16384, wsWl + 6*16384, wbh, wbl, Xh, Xl, l31, lh);
  bias_relu(acc, sB + 4*128, lh);
  build_frags(acc, Xh, Xl, lh);

  zero4(acc);
  run_panel<8,true>(acc, wsWh + 6*16384, wsWl + 6*16384,
                         wsWh + 7*16384, wsWl + 7*16384, wbh, wbl, Xh, Xl, l31, lh);
  bias_relu(acc, sB + 5*128, lh);
  build_frags(acc, Xh, Xl, lh);

  zero4(acc);
  run_panel<8,true>(acc, wsWh + 7*16384, wsWl + 7*16384,
                         wsWh + 8*16384, wsWl + 8*16384, wbh, wbl, Xh, Xl, l31, lh);
  bias_relu(acc, sB + 6*128, lh);
  build_frags(acc, Xh, Xl, lh);

  zero4(acc);
  run_panel<8,false>(acc, wsWh + 8*16384, wsWl + 8*16384,
                          (const ushort_t*)0, (const ushort_t*)0, wbh, wbl, Xh, Xl, l31, lh);

  float* __restrict__ sFw = &sF[wid][0];
  #pragma unroll
  for (int tn = 0; tn < 4; ++tn)
    #pragma unroll
    for (int b = 0; b < 4; ++b) {
      const int n0 = tn*32 + 8*b + 4*lh;
      const float4 bv = *(const float4*)(sB + 7*128 + n0);
      const float v0 = acc[tn][4*b+0] + bv.x;
      const float v1 = acc[tn][4*b+1] + bv.y;
      const float v2 = acc[tn][4*b+2] + bv.z;
      const float v3 = acc[tn][4*b+3] + bv.w;
      *(float4*)(sFw + l31*132 + n0) = make_float4(v0, v1, v2, v3);
      acc[tn][4*b+0] = fmaxf(v0, 0.f);
      acc[tn][4*b+1] = fmaxf(v1, 0.f);
      acc[tn][4*b+2] = fmaxf(v2, 0.f);
      acc[tn][4*b+3] = fmaxf(v3, 0.f);
    }

  asm volatile("s_waitcnt lgkmcnt(0)" ::: "memory");
  __builtin_amdgcn_sched_barrier(0);

  float* __restrict__ out1 = out + (size_t)NPTS * 3;
  #pragma unroll
  for (int i = 0; i < 16; ++i) {
    const int idx = i*64 + lane;
    const int p = idx >> 5, q = idx & 31;
    const float4 v = *(const float4*)(sFw + p*132 + q*4);
    *(float4*)(out1 + (size_t)(p0 + p)*128 + q*4) = v;
  }

  float dotc[3];
  #pragma unroll
  for (int c = 0; c < 3; ++c) {
    float a = 0.f;
    #pragma unroll
    for (int tn = 0; tn < 4; ++tn)
      #pragma unroll
      for (int b = 0; b < 4; ++b) {
        const int n0 = tn*32 + 8*b + 4*lh;
        const float4 w4 = *(const float4*)(sB + 1024 + c*128 + n0);
        a = fmaf(acc[tn][4*b+0], w4.x, a);
        a = fmaf(acc[tn][4*b+1], w4.y, a);
        a = fmaf(acc[tn][4*b+2], w4.z, a);
        a = fmaf(acc[tn][4*b+3], w4.w, a);
      }
    a += __shfl_xor(a, 32, 64);
    dotc[c] = a;
  }
  if (lh == 0) {
    const int g = p0 + l31;
    #pragma unroll
    for (int c = 0; c < 3; ++c)
      out[g*3 + c] = base3[g*3 + c] + dotc[c] + sB[1408 + c];
  }
}

extern "C" void kernel_launch(void* const* d_in, const int* in_sizes, int n_in,
                              void* d_out, int out_size, void* d_ws, size_t ws_size,
                              hipStream_t stream)
{
  const float* pts  = (const float*)d_in[0];
  const float* dm   = (const float*)d_in[1];
  const float* cano = (const float*)d_in[2];
  const float* lat  = (const float*)d_in[3];
  const float* w[8]; const float* b[8];
  for (int i = 0; i < 8; ++i) {
    w[i] = (const float*)d_in[4 + 2*i];
    b[i] = (const float*)d_in[5 + 2*i];
  }
  const float* w_out = (const float*)d_in[20];
  const float* b_out = (const float*)d_in[21];
  float* out = (float*)d_out;

  // ws: feat [NPTS][112] uint (29.36MB) | base3 (786KB) | wsWh (288KB) | wsWl (288KB)
  //     | aFF 2*5120*16B (160KB) | aFH (160KB) | vq 2*5120*16B (160KB)
  uint_t*   feat  = (uint_t*)d_ws;
  float*    base3 = (float*)((char*)d_ws + (size_t)NPTS*FSTR*4);
  ushort_t* wsWh  = (ushort_t*)((char*)base3 + (size_t)NPTS*3*4);
  ushort_t* wsWl  = wsWh + 147456;
  ushort_t* aFF   = wsWl + 147456;
  ushort_t* aFH   = aFF + 2*NVP*8;
  float4*   vq    = (float4*)(aFH + 2*NVP*8);

  k_prep<<<576, 256, 0, stream>>>(dm,
      w[0],w[1],w[2],w[3],w[4],w[5],w[6],w[7], wsWh, wsWl, aFF, aFH, vq);
  k_nnfeat<<<2048, 256, 0, stream>>>(pts, dm, cano, lat, aFF, aFH, vq, feat, base3);
  k_mlp<<<NPTS/128, 256, 0, stream>>>(feat, base3, wsWh, wsWl,
      b[0],b[1],b[2],b[3],b[4],b[5],b[6],b[7], w_out, b_out, out);
}